// Round 1
// 288.857 us; speedup vs baseline: 1.0421x; 1.0421x over previous
//
#include <hip/hip_runtime.h>
#include <hip/hip_bf16.h>

// SPRGraphNet: embed -> 2x SAGEConv(mean) -> mean-pool per graph -> linear(64->10)
// Inputs detected fp32 (round 2). bf16 h (round 8). Sort-based CSR (round 10).
// Round 16: restructure gather_kernel from wave-per-node (8 edge-groups +
// shfl_xor tree reduce + 1/8-lane epilogue) to GROUP-PER-NODE: 8 consecutive
// lanes own one node, lane j accumulates cols [8j,8j+8) over the node's whole
// edge list. Removes 24 ds_swizzle + 24 adds per node (3-deep dependent
// chain), removes the 7/8-idle epilogue, stores 1KB/wave instead of 128B.
// Memory pattern unchanged (8 scattered 128B row segments per wave load).
// Value-identical fp32 accumulation of the same bf16 values.
// Harness poison fills (~83us/iter at 81% HBM peak) = floor.

struct WParams {
    const void* p[10];
    int off[11];
};

__device__ __forceinline__ float b2f(unsigned short u) {
    return __uint_as_float(((unsigned)u) << 16);
}
__device__ __forceinline__ unsigned short f2b(float f) {
    unsigned x = __float_as_uint(f);
    return (unsigned short)((x + 0x7fff + ((x >> 16) & 1)) >> 16);   // RNE
}
__device__ __forceinline__ float4 b4_to_f4(ushort4 u) {
    return make_float4(b2f(u.x), b2f(u.y), b2f(u.z), b2f(u.w));
}
__device__ __forceinline__ float blo(unsigned u) {   // low bf16 of a dword
    return __uint_as_float(u << 16);
}
__device__ __forceinline__ float bhi(unsigned u) {   // high bf16 of a dword
    return __uint_as_float(u & 0xffff0000u);
}

// Inline dtype detection: fp32 data read as bf16 shows |v|>100 / NaN.
__device__ __forceinline__ int detect_f32(const void* probe, int n_bf16) {
    __shared__ int bad;
    if (threadIdx.x == 0) bad = 0;
    __syncthreads();
    const __hip_bfloat16* p = (const __hip_bfloat16*)probe;
    int lbad = 0;
    for (int i = threadIdx.x; i < n_bf16; i += blockDim.x) {
        float v = __bfloat162float(p[i]);
        if (!(fabsf(v) <= 100.0f)) lbad = 1;
    }
    if (lbad) atomicOr(&bad, 1);
    __syncthreads();
    return bad;
}

__device__ __forceinline__ float loadf(const void* p, int i, int f32) {
    return f32 ? ((const float*)p)[i]
               : __bfloat162float(((const __hip_bfloat16*)p)[i]);
}

static __global__ void convert_kernel(WParams wp, const void* probe,
                                      float* __restrict__ dst, int total) {
    int f32 = detect_f32(probe, 1024);
    int gid = blockIdx.x * blockDim.x + threadIdx.x;
    if (gid >= total) return;
    int s = 0;
    while (gid >= wp.off[s + 1]) ++s;
    dst[gid] = loadf(wp.p[s], gid - wp.off[s], f32);
}

// Blocks [0,NBE): LDS histogram of tgt&511 over a 4096-edge tile -> H[bin][blk].
// Blocks [NBE,..): embed (ushort4 per thread).
static __global__ __launch_bounds__(256) void hist1_embed_kernel(
        const int* __restrict__ tgt, int* __restrict__ H, int NBE,
        const int* __restrict__ x,
        const float* __restrict__ semb, const float* __restrict__ cemb,
        unsigned short* __restrict__ h, int n_nodes, int n_edges) {
    if (blockIdx.x < (unsigned)NBE) {
        __shared__ int lh[512];
        int t = threadIdx.x;
        lh[t] = 0; lh[t + 256] = 0;
        __syncthreads();
        int base = blockIdx.x * 4096;              // multiple of 4
        const int4* tgt4 = (const int4*)tgt + (base >> 2);
#pragma unroll
        for (int r = 0; r < 4; ++r) {
            int i4 = t + 256 * r;
            int e = base + i4 * 4;
            if (e + 3 < n_edges) {
                int4 v = tgt4[i4];
                atomicAdd(&lh[v.x & 511], 1);
                atomicAdd(&lh[v.y & 511], 1);
                atomicAdd(&lh[v.z & 511], 1);
                atomicAdd(&lh[v.w & 511], 1);
            } else {
                for (int q = 0; q < 4; ++q) {
                    int ee = e + q;
                    if (ee < n_edges) atomicAdd(&lh[tgt[ee] & 511], 1);
                }
            }
        }
        __syncthreads();
        H[(size_t)t * NBE + blockIdx.x] = lh[t];
        H[(size_t)(t + 256) * NBE + blockIdx.x] = lh[t + 256];
    } else {
        int gid = (blockIdx.x - NBE) * 256 + threadIdx.x;
        int node = gid >> 4, c4 = (gid & 15) * 4;
        if (node >= n_nodes) return;
        const float* tab;
        int row, c = c4;
        if (c4 < 32) { tab = semb; row = x[node * 2]; }
        else         { tab = cemb; row = x[node * 2 + 1]; c = c4 - 32; }
        const float* p = tab + (size_t)row * 32 + c;
        ushort4 o;
        o.x = f2b(p[0]); o.y = f2b(p[1]); o.z = f2b(p[2]); o.w = f2b(p[3]);
        *(ushort4*)&h[(size_t)node * 64 + c4] = o;
    }
}

// scanA: 512 elements per block (2/thread), block-inclusive -> tmp, sums -> bsum.
static __global__ __launch_bounds__(256) void scanA_kernel(
        const int* __restrict__ in, int* __restrict__ tmp,
        int* __restrict__ bsum, int n) {
    __shared__ int s[256];
    int t = threadIdx.x;
    int i0 = blockIdx.x * 512 + 2 * t;
    int a0 = (i0 < n) ? in[i0] : 0;
    int a1 = (i0 + 1 < n) ? in[i0 + 1] : 0;
    s[t] = a0 + a1;
    __syncthreads();
#pragma unroll
    for (int d = 1; d < 256; d <<= 1) {
        int x = (t >= d) ? s[t - d] : 0;
        __syncthreads();
        s[t] += x;
        __syncthreads();
    }
    if (i0 < n) tmp[i0] = s[t] - a1;          // inclusive at i0
    if (i0 + 1 < n) tmp[i0 + 1] = s[t];       // inclusive at i0+1
    if (t == 255) bsum[blockIdx.x] = s[255];
}

static __global__ __launch_bounds__(1024) void scan2_kernel(
        int* __restrict__ bsum, int nb) {     // in-place inclusive scan, nb <= 1024
    __shared__ int s[1024];
    int t = threadIdx.x;
    s[t] = (t < nb) ? bsum[t] : 0;
    __syncthreads();
#pragma unroll
    for (int d = 1; d < 1024; d <<= 1) {
        int x = (t >= d) ? s[t - d] : 0;
        __syncthreads();
        s[t] += x;
        __syncthreads();
    }
    if (t < nb) bsum[t] = s[t];
}

// scanC: B[i] = global exclusive prefix of H at i.
static __global__ __launch_bounds__(256) void scanC_kernel(
        const int* __restrict__ tmp, const int* __restrict__ bsum,
        const int* __restrict__ H, int* __restrict__ B, int n) {
    int i = blockIdx.x * 256 + threadIdx.x;
    if (i >= n) return;
    int blk = i / 512;
    int basep = (blk > 0) ? bsum[blk - 1] : 0;
    B[i] = tmp[i] + basep - H[i];
}

// scatter1: re-read tile; LDS cursors seeded from B give global slots directly.
// Write packed 32-bit records ((tgt>>9)<<17 | src) grouped by bucket.
static __global__ __launch_bounds__(256) void scatter1_kernel(
        const int* __restrict__ src, const int* __restrict__ tgt,
        const int* __restrict__ B, unsigned* __restrict__ rec,
        int NBE, int n_edges) {
    __shared__ int cur[512];
    int t = threadIdx.x;
    cur[t]       = B[(size_t)t * NBE + blockIdx.x];
    cur[t + 256] = B[(size_t)(t + 256) * NBE + blockIdx.x];
    __syncthreads();
    int base = blockIdx.x * 4096;
    const int4* tgt4 = (const int4*)tgt + (base >> 2);
    const int4* src4 = (const int4*)src + (base >> 2);
#pragma unroll
    for (int r = 0; r < 4; ++r) {
        int i4 = t + 256 * r;
        int e = base + i4 * 4;
        if (e + 3 < n_edges) {
            int4 tv = tgt4[i4];
            int4 sv = src4[i4];
            int p0 = atomicAdd(&cur[tv.x & 511], 1);
            rec[p0] = ((unsigned)(tv.x >> 9) << 17) | (unsigned)sv.x;
            int p1 = atomicAdd(&cur[tv.y & 511], 1);
            rec[p1] = ((unsigned)(tv.y >> 9) << 17) | (unsigned)sv.y;
            int p2 = atomicAdd(&cur[tv.z & 511], 1);
            rec[p2] = ((unsigned)(tv.z >> 9) << 17) | (unsigned)sv.z;
            int p3 = atomicAdd(&cur[tv.w & 511], 1);
            rec[p3] = ((unsigned)(tv.w >> 9) << 17) | (unsigned)sv.w;
        } else {
            for (int q = 0; q < 4; ++q) {
                int ee = e + q;
                if (ee < n_edges) {
                    int tg = tgt[ee];
                    int pos = atomicAdd(&cur[tg & 511], 1);
                    rec[pos] = ((unsigned)(tg >> 9) << 17) | (unsigned)src[ee];
                }
            }
        }
    }
}

// csr2: one block per bucket b. Records [B[b*NBE], next) share tgt&511==b;
// q = rec>>17 (<196), node = b + (q<<9). LDS hist+scan -> start/cnt + scatter.
static __global__ __launch_bounds__(256) void csr2_kernel(
        const unsigned* __restrict__ rec, const int* __restrict__ B,
        int NBE, int* __restrict__ csr_src,
        int* __restrict__ startA, int* __restrict__ cntA,
        int n_nodes, int n_edges) {
    __shared__ int hist[256], scn[256], cursor[256];
    __shared__ int sbeg, send;
    int b = blockIdx.x;
    int t = threadIdx.x;
    hist[t] = 0;
    if (t == 0) {
        sbeg = B[(size_t)b * NBE];
        send = (b == 511) ? n_edges : B[(size_t)(b + 1) * NBE];
    }
    __syncthreads();
    int beg = sbeg, end = send;
    for (int i = beg + t; i < end; i += 256) {
        atomicAdd(&hist[rec[i] >> 17], 1);
    }
    __syncthreads();
    scn[t] = hist[t];
    __syncthreads();
#pragma unroll
    for (int d = 1; d < 256; d <<= 1) {
        int x = (t >= d) ? scn[t - d] : 0;
        __syncthreads();
        scn[t] += x;
        __syncthreads();
    }
    int excl = scn[t] - hist[t];
    cursor[t] = beg + excl;
    int n = b + (t << 9);
    if (n < n_nodes) { startA[n] = beg + excl; cntA[n] = hist[t]; }
    __syncthreads();
    for (int i = beg + t; i < end; i += 256) {
        unsigned r = rec[i];
        int p = atomicAdd(&cursor[r >> 17], 1);
        csr_src[p] = (int)(r & 0x1FFFFu);
    }
}

// Round 16: GROUP-PER-NODE gather. 8 consecutive lanes own one node; lane j
// accumulates cols [8j,8j+8) (one ushort8 = 16B per edge) over the node's
// whole edge list. Per wave: 8 CSR-adjacent nodes. Row loads are the same
// 8-scattered-128B-segments-per-wave-instruction pattern as before; csr_src
// broadcast loads now span 8 adjacent edge ranges (better L1/L2 locality).
// No cross-lane reduce, no masked epilogue, full-width 1KB/wave stores.
static __global__ __launch_bounds__(256) void gather_kernel(
        const unsigned short* __restrict__ h, const int* __restrict__ startA,
        const int* __restrict__ cntA,
        const int* __restrict__ csr_src, unsigned short* __restrict__ aggb,
        int n_nodes) {
    int node = (blockIdx.x * 256 + threadIdx.x) >> 3;
    int j = threadIdx.x & 7;                 // cols [8j, 8j+8)
    if (node >= n_nodes) return;
    int beg = startA[node], deg = cntA[node];

    float acc[8];
#pragma unroll
    for (int k = 0; k < 8; ++k) acc[k] = 0.f;

    const unsigned short* hj = h + j * 8;
    int it = 0;
    for (; it + 1 < deg; it += 2) {
        int s0 = csr_src[beg + it];
        int s1 = csr_src[beg + it + 1];
        uint4 u0 = *reinterpret_cast<const uint4*>(hj + (size_t)s0 * 64);
        uint4 u1 = *reinterpret_cast<const uint4*>(hj + (size_t)s1 * 64);
        acc[0] += blo(u0.x) + blo(u1.x);
        acc[1] += bhi(u0.x) + bhi(u1.x);
        acc[2] += blo(u0.y) + blo(u1.y);
        acc[3] += bhi(u0.y) + bhi(u1.y);
        acc[4] += blo(u0.z) + blo(u1.z);
        acc[5] += bhi(u0.z) + bhi(u1.z);
        acc[6] += blo(u0.w) + blo(u1.w);
        acc[7] += bhi(u0.w) + bhi(u1.w);
    }
    if (it < deg) {
        int s = csr_src[beg + it];
        uint4 u = *reinterpret_cast<const uint4*>(hj + (size_t)s * 64);
        acc[0] += blo(u.x); acc[1] += bhi(u.x);
        acc[2] += blo(u.y); acc[3] += bhi(u.y);
        acc[4] += blo(u.z); acc[5] += bhi(u.z);
        acc[6] += blo(u.w); acc[7] += bhi(u.w);
    }
    float inv = 1.0f / fmaxf((float)deg, 1.0f);
    uint4 o;
    o.x = ((unsigned)f2b(acc[1] * inv) << 16) | f2b(acc[0] * inv);
    o.y = ((unsigned)f2b(acc[3] * inv) << 16) | f2b(acc[2] * inv);
    o.z = ((unsigned)f2b(acc[5] * inv) << 16) | f2b(acc[4] * inv);
    o.w = ((unsigned)f2b(acc[7] * inv) << 16) | f2b(acc[6] * inv);
    *reinterpret_cast<uint4*>(aggb + (size_t)node * 64 + j * 8) = o;
}

// h = relu([agg | h] @ [wl; wr] + b), in place (bf16 h + bf16 agg, fp32 math).
static __global__ __launch_bounds__(256) void layer_kernel(
        unsigned short* __restrict__ h, const unsigned short* __restrict__ aggb,
        const float* __restrict__ wl, const float* __restrict__ wr,
        const float* __restrict__ b, int n_nodes) {
    __shared__ float inS[64][132];   // [node][k], +4 pad
    __shared__ float wS[128][64];    // [k][col], rows 0..63 = wl, 64..127 = wr
    int t = threadIdx.x;
    int base = blockIdx.x * 64;

    const float4* wl4 = (const float4*)wl;
    const float4* wr4 = (const float4*)wr;
#pragma unroll
    for (int r = 0; r < 4; ++r) {
        int i = t + 256 * r;
        int k = i >> 4, c = (i & 15) * 4;
        *(float4*)&wS[k][c] = wl4[i];
        *(float4*)&wS[64 + k][c] = wr4[i];
    }
#pragma unroll
    for (int r = 0; r < 4; ++r) {
        int i = t + 256 * r;
        int n = i >> 4, c = (i & 15) * 4;
        int node = base + n;
        float4 va = make_float4(0.f, 0.f, 0.f, 0.f);
        float4 vh = make_float4(0.f, 0.f, 0.f, 0.f);
        if (node < n_nodes) {
            va = b4_to_f4(*(const ushort4*)&aggb[(size_t)node * 64 + c]);
            vh = b4_to_f4(*(const ushort4*)&h[(size_t)node * 64 + c]);
        }
        *(float4*)&inS[n][c] = va;
        *(float4*)&inS[n][64 + c] = vh;
    }
    __syncthreads();

    int tx = t & 15, ty = t >> 4;
    int c0 = tx * 4, n0 = ty * 4;
    float4 bias = *(const float4*)&b[c0];
    float acc[4][4];
#pragma unroll
    for (int i = 0; i < 4; ++i) {
        acc[i][0] = bias.x; acc[i][1] = bias.y;
        acc[i][2] = bias.z; acc[i][3] = bias.w;
    }

#pragma unroll 4
    for (int k = 0; k < 128; k += 4) {
        float4 a0 = *(const float4*)&inS[n0 + 0][k];
        float4 a1 = *(const float4*)&inS[n0 + 1][k];
        float4 a2 = *(const float4*)&inS[n0 + 2][k];
        float4 a3 = *(const float4*)&inS[n0 + 3][k];
        float4 w0 = *(const float4*)&wS[k + 0][c0];
        float4 w1 = *(const float4*)&wS[k + 1][c0];
        float4 w2 = *(const float4*)&wS[k + 2][c0];
        float4 w3 = *(const float4*)&wS[k + 3][c0];
#define ROW(i, ai)                                                        \
        acc[i][0] = fmaf(ai.x, w0.x, fmaf(ai.y, w1.x, fmaf(ai.z, w2.x,    \
                    fmaf(ai.w, w3.x, acc[i][0]))));                       \
        acc[i][1] = fmaf(ai.x, w0.y, fmaf(ai.y, w1.y, fmaf(ai.z, w2.y,    \
                    fmaf(ai.w, w3.y, acc[i][1]))));                       \
        acc[i][2] = fmaf(ai.x, w0.z, fmaf(ai.y, w1.z, fmaf(ai.z, w2.z,    \
                    fmaf(ai.w, w3.z, acc[i][2]))));                       \
        acc[i][3] = fmaf(ai.x, w0.w, fmaf(ai.y, w1.w, fmaf(ai.z, w2.w,    \
                    fmaf(ai.w, w3.w, acc[i][3]))));
        ROW(0, a0) ROW(1, a1) ROW(2, a2) ROW(3, a3)
#undef ROW
    }

#pragma unroll
    for (int i = 0; i < 4; ++i) {
        int node = base + n0 + i;
        if (node < n_nodes) {
            ushort4 o;
            o.x = f2b(fmaxf(acc[i][0], 0.f));
            o.y = f2b(fmaxf(acc[i][1], 0.f));
            o.z = f2b(fmaxf(acc[i][2], 0.f));
            o.w = f2b(fmaxf(acc[i][3], 0.f));
            *(ushort4*)&h[(size_t)node * 64 + c0] = o;
        }
    }
}

// batch is sorted: binary-search [start,end) per graph; mean-pool then classify.
static __global__ __launch_bounds__(256) void pool_classify_kernel(
        const unsigned short* __restrict__ h, const int* __restrict__ batch,
        const float* __restrict__ wc, const float* __restrict__ bc,
        void* __restrict__ out, const void* probe, int n_nodes) {
    int f32 = detect_f32(probe, 1024);
    int g = blockIdx.x;
    int t = threadIdx.x;
    int lo = 0, hi = n_nodes;
    while (lo < hi) { int mid = (lo + hi) >> 1; if (batch[mid] < g) lo = mid + 1; else hi = mid; }
    int start = lo;
    hi = n_nodes;
    while (lo < hi) { int mid = (lo + hi) >> 1; if (batch[mid] < g + 1) lo = mid + 1; else hi = mid; }
    int end = lo;

    int r = t >> 6, o = t & 63;
    float partial = 0.0f;
    for (int n = start + r; n < end; n += 4) partial += b2f(h[(size_t)n * 64 + o]);
    __shared__ float sred[4][64];
    __shared__ float pooled[64];
    sred[r][o] = partial;
    __syncthreads();
    if (r == 0) {
        float cntf = fmaxf((float)(end - start), 1.0f);
        pooled[o] = (sred[0][o] + sred[1][o] + sred[2][o] + sred[3][o]) / cntf;
    }
    __syncthreads();
    if (t < 10) {
        float acc = bc[t];
#pragma unroll
        for (int k = 0; k < 64; ++k)
            acc = fmaf(pooled[k], wc[k * 10 + t], acc);
        if (f32) ((float*)out)[g * 10 + t] = acc;
        else     ((__hip_bfloat16*)out)[g * 10 + t] = __float2bfloat16(acc);
    }
}

extern "C" void kernel_launch(void* const* d_in, const int* in_sizes, int n_in,
                              void* d_out, int out_size, void* d_ws, size_t ws_size,
                              hipStream_t stream) {
    const int* x          = (const int*)d_in[0];
    const int* edge_index = (const int*)d_in[1];
    const int* batch      = (const int*)d_in[2];

    const int N = in_sizes[2];        // N_NODES
    const int E = in_sizes[1] / 2;    // edge_index is (2, E)
    const int G = out_size / 10;      // num_graphs

    const int NBE = (E + 4095) / 4096;          // edge tiles
    const int Hsz = 512 * NBE;                  // histogram matrix size
    const int SB  = (Hsz + 511) / 512;          // scanA blocks (<=1024)
    const int MB  = (N * 16 + 255) / 256;       // embed blocks

    // workspace layout
    unsigned short* h    = (unsigned short*)d_ws;           // N*64 bf16
    unsigned short* aggb = h + (size_t)N * 64;              // N*64 bf16
    unsigned* rec   = (unsigned*)(aggb + (size_t)N * 64);   // E packed
    int*   startA  = (int*)(rec + E);                       // N
    int*   cntA    = startA + N;                            // N
    int*   H       = cntA + N;                              // Hsz
    int*   B       = H + Hsz;                               // Hsz
    int*   tmpS    = B + Hsz;                               // Hsz
    int*   bsumS   = tmpS + Hsz;                            // SB (<=1024)
    int*   csr_src = bsumS + 1024;                          // E
    float* wbuf    = (float*)(csr_src + E);

    WParams wp;
    int off = 0;
    for (int i = 0; i < 10; ++i) {
        wp.p[i] = d_in[4 + i];
        wp.off[i] = off;
        off += in_sizes[4 + i];
    }
    wp.off[10] = off;
    const int wtotal = off;

    float* semb_f = wbuf + wp.off[0];
    float* cemb_f = wbuf + wp.off[1];
    float* w1l_f  = wbuf + wp.off[2];
    float* w1r_f  = wbuf + wp.off[3];
    float* b1_f   = wbuf + wp.off[4];
    float* w2l_f  = wbuf + wp.off[5];
    float* w2r_f  = wbuf + wp.off[6];
    float* b2_f   = wbuf + wp.off[7];
    float* wc_f   = wbuf + wp.off[8];
    float* bc_f   = wbuf + wp.off[9];

    const int* src = edge_index;
    const int* tgt = edge_index + E;

    convert_kernel<<<(wtotal + 255) / 256, 256, 0, stream>>>(wp, d_in[4], wbuf, wtotal);

    // CSR build by counting sort (no global returning atomics, no memset)
    hist1_embed_kernel<<<NBE + MB, 256, 0, stream>>>(tgt, H, NBE, x, semb_f,
                                                     cemb_f, h, N, E);
    scanA_kernel<<<SB, 256, 0, stream>>>(H, tmpS, bsumS, Hsz);
    scan2_kernel<<<1, 1024, 0, stream>>>(bsumS, SB);
    scanC_kernel<<<(Hsz + 255) / 256, 256, 0, stream>>>(tmpS, bsumS, H, B, Hsz);
    scatter1_kernel<<<NBE, 256, 0, stream>>>(src, tgt, B, rec, NBE, E);
    csr2_kernel<<<512, 256, 0, stream>>>(rec, B, NBE, csr_src, startA, cntA, N, E);

    // layer 1
    gather_kernel<<<(N * 8 + 255) / 256, 256, 0, stream>>>(h, startA, cntA, csr_src, aggb, N);
    layer_kernel<<<(N + 63) / 64, 256, 0, stream>>>(h, aggb, w1l_f, w1r_f, b1_f, N);

    // layer 2
    gather_kernel<<<(N * 8 + 255) / 256, 256, 0, stream>>>(h, startA, cntA, csr_src, aggb, N);
    layer_kernel<<<(N + 63) / 64, 256, 0, stream>>>(h, aggb, w2l_f, w2r_f, b2_f, N);

    // pool + classify
    pool_classify_kernel<<<G, 256, 0, stream>>>(h, batch, wc_f, bc_f, d_out, d_in[4], N);
}

// Round 2
// 278.367 us; speedup vs baseline: 1.0813x; 1.0377x over previous
//
#include <hip/hip_runtime.h>
#include <hip/hip_bf16.h>

// SPRGraphNet: embed -> 2x SAGEConv(mean) -> mean-pool per graph -> linear(64->10)
// Inputs detected fp32 (round 2). bf16 h (round 8). Sort-based CSR (round 10).
// Round 16: group-per-node gather (8 lanes/node, no shfl reduce).
// Round 17: layer-1 gather via LDS embedding table. h[src] for layer 1 is
// [semb[x0]|cemb[x1]] -> only 1024 distinct rows (10KB). hist1_embed emits
// code[node] = x0*16+x1; csr2 packs it into the CSR record ((code<<17)|src);
// gather1 looks rows up in LDS (row stride 80B for bank spread) instead of
// gathering 128B random rows from HBM/L2 (~80MB fetch -> ~20MB). Same bf16
// values, same accumulation order => absmax unchanged. gather2 (arbitrary h)
// keeps the round-16 structure, masking src with 0x1FFFF.
// Harness poison fills (~83us/iter at 81% HBM peak) = floor.

struct WParams {
    const void* p[10];
    int off[11];
};

__device__ __forceinline__ float b2f(unsigned short u) {
    return __uint_as_float(((unsigned)u) << 16);
}
__device__ __forceinline__ unsigned short f2b(float f) {
    unsigned x = __float_as_uint(f);
    return (unsigned short)((x + 0x7fff + ((x >> 16) & 1)) >> 16);   // RNE
}
__device__ __forceinline__ float4 b4_to_f4(ushort4 u) {
    return make_float4(b2f(u.x), b2f(u.y), b2f(u.z), b2f(u.w));
}
__device__ __forceinline__ float blo(unsigned u) {   // low bf16 of a dword
    return __uint_as_float(u << 16);
}
__device__ __forceinline__ float bhi(unsigned u) {   // high bf16 of a dword
    return __uint_as_float(u & 0xffff0000u);
}

// Inline dtype detection: fp32 data read as bf16 shows |v|>100 / NaN.
__device__ __forceinline__ int detect_f32(const void* probe, int n_bf16) {
    __shared__ int bad;
    if (threadIdx.x == 0) bad = 0;
    __syncthreads();
    const __hip_bfloat16* p = (const __hip_bfloat16*)probe;
    int lbad = 0;
    for (int i = threadIdx.x; i < n_bf16; i += blockDim.x) {
        float v = __bfloat162float(p[i]);
        if (!(fabsf(v) <= 100.0f)) lbad = 1;
    }
    if (lbad) atomicOr(&bad, 1);
    __syncthreads();
    return bad;
}

__device__ __forceinline__ float loadf(const void* p, int i, int f32) {
    return f32 ? ((const float*)p)[i]
               : __bfloat162float(((const __hip_bfloat16*)p)[i]);
}

static __global__ void convert_kernel(WParams wp, const void* probe,
                                      float* __restrict__ dst, int total) {
    int f32 = detect_f32(probe, 1024);
    int gid = blockIdx.x * blockDim.x + threadIdx.x;
    if (gid >= total) return;
    int s = 0;
    while (gid >= wp.off[s + 1]) ++s;
    dst[gid] = loadf(wp.p[s], gid - wp.off[s], f32);
}

// Blocks [0,NBE): LDS histogram of tgt&511 over a 4096-edge tile -> H[bin][blk].
// Blocks [NBE,..): embed (ushort4 per thread) + code[node] = x0*16+x1.
static __global__ __launch_bounds__(256) void hist1_embed_kernel(
        const int* __restrict__ tgt, int* __restrict__ H, int NBE,
        const int* __restrict__ x,
        const float* __restrict__ semb, const float* __restrict__ cemb,
        unsigned short* __restrict__ h, unsigned short* __restrict__ code,
        int n_nodes, int n_edges) {
    if (blockIdx.x < (unsigned)NBE) {
        __shared__ int lh[512];
        int t = threadIdx.x;
        lh[t] = 0; lh[t + 256] = 0;
        __syncthreads();
        int base = blockIdx.x * 4096;              // multiple of 4
        const int4* tgt4 = (const int4*)tgt + (base >> 2);
#pragma unroll
        for (int r = 0; r < 4; ++r) {
            int i4 = t + 256 * r;
            int e = base + i4 * 4;
            if (e + 3 < n_edges) {
                int4 v = tgt4[i4];
                atomicAdd(&lh[v.x & 511], 1);
                atomicAdd(&lh[v.y & 511], 1);
                atomicAdd(&lh[v.z & 511], 1);
                atomicAdd(&lh[v.w & 511], 1);
            } else {
                for (int q = 0; q < 4; ++q) {
                    int ee = e + q;
                    if (ee < n_edges) atomicAdd(&lh[tgt[ee] & 511], 1);
                }
            }
        }
        __syncthreads();
        H[(size_t)t * NBE + blockIdx.x] = lh[t];
        H[(size_t)(t + 256) * NBE + blockIdx.x] = lh[t + 256];
    } else {
        int gid = (blockIdx.x - NBE) * 256 + threadIdx.x;
        int node = gid >> 4, c4 = (gid & 15) * 4;
        if (node >= n_nodes) return;
        const float* tab;
        int row, c = c4;
        if (c4 < 32) { tab = semb; row = x[node * 2]; }
        else         { tab = cemb; row = x[node * 2 + 1]; c = c4 - 32; }
        if (c4 == 0) {
            code[node] = (unsigned short)(x[node * 2] * 16 + x[node * 2 + 1]);
        }
        const float* p = tab + (size_t)row * 32 + c;
        ushort4 o;
        o.x = f2b(p[0]); o.y = f2b(p[1]); o.z = f2b(p[2]); o.w = f2b(p[3]);
        *(ushort4*)&h[(size_t)node * 64 + c4] = o;
    }
}

// scanA: 512 elements per block (2/thread), block-inclusive -> tmp, sums -> bsum.
static __global__ __launch_bounds__(256) void scanA_kernel(
        const int* __restrict__ in, int* __restrict__ tmp,
        int* __restrict__ bsum, int n) {
    __shared__ int s[256];
    int t = threadIdx.x;
    int i0 = blockIdx.x * 512 + 2 * t;
    int a0 = (i0 < n) ? in[i0] : 0;
    int a1 = (i0 + 1 < n) ? in[i0 + 1] : 0;
    s[t] = a0 + a1;
    __syncthreads();
#pragma unroll
    for (int d = 1; d < 256; d <<= 1) {
        int x = (t >= d) ? s[t - d] : 0;
        __syncthreads();
        s[t] += x;
        __syncthreads();
    }
    if (i0 < n) tmp[i0] = s[t] - a1;          // inclusive at i0
    if (i0 + 1 < n) tmp[i0 + 1] = s[t];       // inclusive at i0+1
    if (t == 255) bsum[blockIdx.x] = s[255];
}

static __global__ __launch_bounds__(1024) void scan2_kernel(
        int* __restrict__ bsum, int nb) {     // in-place inclusive scan, nb <= 1024
    __shared__ int s[1024];
    int t = threadIdx.x;
    s[t] = (t < nb) ? bsum[t] : 0;
    __syncthreads();
#pragma unroll
    for (int d = 1; d < 1024; d <<= 1) {
        int x = (t >= d) ? s[t - d] : 0;
        __syncthreads();
        s[t] += x;
        __syncthreads();
    }
    if (t < nb) bsum[t] = s[t];
}

// scanC: B[i] = global exclusive prefix of H at i.
static __global__ __launch_bounds__(256) void scanC_kernel(
        const int* __restrict__ tmp, const int* __restrict__ bsum,
        const int* __restrict__ H, int* __restrict__ B, int n) {
    int i = blockIdx.x * 256 + threadIdx.x;
    if (i >= n) return;
    int blk = i / 512;
    int basep = (blk > 0) ? bsum[blk - 1] : 0;
    B[i] = tmp[i] + basep - H[i];
}

// scatter1: re-read tile; LDS cursors seeded from B give global slots directly.
// Write packed 32-bit records ((tgt>>9)<<17 | src) grouped by bucket.
static __global__ __launch_bounds__(256) void scatter1_kernel(
        const int* __restrict__ src, const int* __restrict__ tgt,
        const int* __restrict__ B, unsigned* __restrict__ rec,
        int NBE, int n_edges) {
    __shared__ int cur[512];
    int t = threadIdx.x;
    cur[t]       = B[(size_t)t * NBE + blockIdx.x];
    cur[t + 256] = B[(size_t)(t + 256) * NBE + blockIdx.x];
    __syncthreads();
    int base = blockIdx.x * 4096;
    const int4* tgt4 = (const int4*)tgt + (base >> 2);
    const int4* src4 = (const int4*)src + (base >> 2);
#pragma unroll
    for (int r = 0; r < 4; ++r) {
        int i4 = t + 256 * r;
        int e = base + i4 * 4;
        if (e + 3 < n_edges) {
            int4 tv = tgt4[i4];
            int4 sv = src4[i4];
            int p0 = atomicAdd(&cur[tv.x & 511], 1);
            rec[p0] = ((unsigned)(tv.x >> 9) << 17) | (unsigned)sv.x;
            int p1 = atomicAdd(&cur[tv.y & 511], 1);
            rec[p1] = ((unsigned)(tv.y >> 9) << 17) | (unsigned)sv.y;
            int p2 = atomicAdd(&cur[tv.z & 511], 1);
            rec[p2] = ((unsigned)(tv.z >> 9) << 17) | (unsigned)sv.z;
            int p3 = atomicAdd(&cur[tv.w & 511], 1);
            rec[p3] = ((unsigned)(tv.w >> 9) << 17) | (unsigned)sv.w;
        } else {
            for (int q = 0; q < 4; ++q) {
                int ee = e + q;
                if (ee < n_edges) {
                    int tg = tgt[ee];
                    int pos = atomicAdd(&cur[tg & 511], 1);
                    rec[pos] = ((unsigned)(tg >> 9) << 17) | (unsigned)src[ee];
                }
            }
        }
    }
}

// csr2: one block per bucket b. Records [B[b*NBE], next) share tgt&511==b;
// q = rec>>17 (<196), node = b + (q<<9). LDS hist+scan -> start/cnt + scatter.
// Round 17: emit packed (code[src]<<17)|src so gather1 needs no node lookup.
static __global__ __launch_bounds__(256) void csr2_kernel(
        const unsigned* __restrict__ rec, const int* __restrict__ B,
        int NBE, const unsigned short* __restrict__ code,
        unsigned* __restrict__ csr_packed,
        int* __restrict__ startA, int* __restrict__ cntA,
        int n_nodes, int n_edges) {
    __shared__ int hist[256], scn[256], cursor[256];
    __shared__ int sbeg, send;
    int b = blockIdx.x;
    int t = threadIdx.x;
    hist[t] = 0;
    if (t == 0) {
        sbeg = B[(size_t)b * NBE];
        send = (b == 511) ? n_edges : B[(size_t)(b + 1) * NBE];
    }
    __syncthreads();
    int beg = sbeg, end = send;
    for (int i = beg + t; i < end; i += 256) {
        atomicAdd(&hist[rec[i] >> 17], 1);
    }
    __syncthreads();
    scn[t] = hist[t];
    __syncthreads();
#pragma unroll
    for (int d = 1; d < 256; d <<= 1) {
        int x = (t >= d) ? scn[t - d] : 0;
        __syncthreads();
        scn[t] += x;
        __syncthreads();
    }
    int excl = scn[t] - hist[t];
    cursor[t] = beg + excl;
    int n = b + (t << 9);
    if (n < n_nodes) { startA[n] = beg + excl; cntA[n] = hist[t]; }
    __syncthreads();
    for (int i = beg + t; i < end; i += 256) {
        unsigned r = rec[i];
        unsigned s = r & 0x1FFFFu;
        unsigned cd = code[s];                 // 200KB table, L2-resident
        int p = atomicAdd(&cursor[r >> 17], 1);
        csr_packed[p] = (cd << 17) | s;
    }
}

// Round 17: layer-1 gather from LDS embedding table. 8 lanes per node; lane j
// owns cols [8j,8j+8). Row for code c is [semb[c>>4] | cemb[c&15]]: lanes 0-3
// read semb LDS, lanes 4-7 read cemb LDS. Row stride 20 uints (80B) => 8
// distinct bank offsets across random codes (breaks same-bank alignment).
// bf16 values identical to h rows; accumulation order identical to gather2.
static __global__ __launch_bounds__(256) void gather1_kernel(
        const float* __restrict__ semb, const float* __restrict__ cemb,
        const int* __restrict__ startA, const int* __restrict__ cntA,
        const unsigned* __restrict__ csr_packed, unsigned short* __restrict__ aggb,
        int n_nodes) {
    __shared__ __align__(16) unsigned sT[64 * 20];   // 5120B
    __shared__ __align__(16) unsigned cT[16 * 20];   // 1280B
    int t = threadIdx.x;
    for (int i = t; i < 64 * 16; i += 256) {
        int r = i >> 4, c = i & 15;
        float lo = semb[r * 32 + c * 2], hi = semb[r * 32 + c * 2 + 1];
        sT[r * 20 + c] = ((unsigned)f2b(hi) << 16) | f2b(lo);
    }
    for (int i = t; i < 16 * 16; i += 256) {
        int r = i >> 4, c = i & 15;
        float lo = cemb[r * 32 + c * 2], hi = cemb[r * 32 + c * 2 + 1];
        cT[r * 20 + c] = ((unsigned)f2b(hi) << 16) | f2b(lo);
    }
    __syncthreads();

    int node = (blockIdx.x * 256 + t) >> 3;
    int j = t & 7;                           // cols [8j, 8j+8)
    if (node >= n_nodes) return;
    int beg = startA[node], deg = cntA[node];

    const uint4* sT4 = (const uint4*)sT;     // row = 5 uint4
    const uint4* cT4 = (const uint4*)cT;
    int js = j, jc = j - 4;                  // lane's block within sub-table

    float acc[8];
#pragma unroll
    for (int k = 0; k < 8; ++k) acc[k] = 0.f;

    int it = 0;
    for (; it + 1 < deg; it += 2) {
        unsigned p0 = csr_packed[beg + it];
        unsigned p1 = csr_packed[beg + it + 1];
        unsigned c0 = p0 >> 17, c1 = p1 >> 17;
        const uint4* a0 = (j < 4) ? sT4 + (c0 >> 4) * 5 + js
                                  : cT4 + (c0 & 15) * 5 + jc;
        const uint4* a1 = (j < 4) ? sT4 + (c1 >> 4) * 5 + js
                                  : cT4 + (c1 & 15) * 5 + jc;
        uint4 u0 = *a0;
        uint4 u1 = *a1;
        acc[0] += blo(u0.x) + blo(u1.x);
        acc[1] += bhi(u0.x) + bhi(u1.x);
        acc[2] += blo(u0.y) + blo(u1.y);
        acc[3] += bhi(u0.y) + bhi(u1.y);
        acc[4] += blo(u0.z) + blo(u1.z);
        acc[5] += bhi(u0.z) + bhi(u1.z);
        acc[6] += blo(u0.w) + blo(u1.w);
        acc[7] += bhi(u0.w) + bhi(u1.w);
    }
    if (it < deg) {
        unsigned p0 = csr_packed[beg + it];
        unsigned c0 = p0 >> 17;
        const uint4* a0 = (j < 4) ? sT4 + (c0 >> 4) * 5 + js
                                  : cT4 + (c0 & 15) * 5 + jc;
        uint4 u = *a0;
        acc[0] += blo(u.x); acc[1] += bhi(u.x);
        acc[2] += blo(u.y); acc[3] += bhi(u.y);
        acc[4] += blo(u.z); acc[5] += bhi(u.z);
        acc[6] += blo(u.w); acc[7] += bhi(u.w);
    }
    float inv = 1.0f / fmaxf((float)deg, 1.0f);
    uint4 o;
    o.x = ((unsigned)f2b(acc[1] * inv) << 16) | f2b(acc[0] * inv);
    o.y = ((unsigned)f2b(acc[3] * inv) << 16) | f2b(acc[2] * inv);
    o.z = ((unsigned)f2b(acc[5] * inv) << 16) | f2b(acc[4] * inv);
    o.w = ((unsigned)f2b(acc[7] * inv) << 16) | f2b(acc[6] * inv);
    *reinterpret_cast<uint4*>(aggb + (size_t)node * 64 + j * 8) = o;
}

// Round 16 gather (layer 2): group-per-node, 8 lanes/node, lane j cols [8j,8j+8).
static __global__ __launch_bounds__(256) void gather_kernel(
        const unsigned short* __restrict__ h, const int* __restrict__ startA,
        const int* __restrict__ cntA,
        const unsigned* __restrict__ csr_packed, unsigned short* __restrict__ aggb,
        int n_nodes) {
    int node = (blockIdx.x * 256 + threadIdx.x) >> 3;
    int j = threadIdx.x & 7;                 // cols [8j, 8j+8)
    if (node >= n_nodes) return;
    int beg = startA[node], deg = cntA[node];

    float acc[8];
#pragma unroll
    for (int k = 0; k < 8; ++k) acc[k] = 0.f;

    const unsigned short* hj = h + j * 8;
    int it = 0;
    for (; it + 1 < deg; it += 2) {
        int s0 = (int)(csr_packed[beg + it] & 0x1FFFFu);
        int s1 = (int)(csr_packed[beg + it + 1] & 0x1FFFFu);
        uint4 u0 = *reinterpret_cast<const uint4*>(hj + (size_t)s0 * 64);
        uint4 u1 = *reinterpret_cast<const uint4*>(hj + (size_t)s1 * 64);
        acc[0] += blo(u0.x) + blo(u1.x);
        acc[1] += bhi(u0.x) + bhi(u1.x);
        acc[2] += blo(u0.y) + blo(u1.y);
        acc[3] += bhi(u0.y) + bhi(u1.y);
        acc[4] += blo(u0.z) + blo(u1.z);
        acc[5] += bhi(u0.z) + bhi(u1.z);
        acc[6] += blo(u0.w) + blo(u1.w);
        acc[7] += bhi(u0.w) + bhi(u1.w);
    }
    if (it < deg) {
        int s = (int)(csr_packed[beg + it] & 0x1FFFFu);
        uint4 u = *reinterpret_cast<const uint4*>(hj + (size_t)s * 64);
        acc[0] += blo(u.x); acc[1] += bhi(u.x);
        acc[2] += blo(u.y); acc[3] += bhi(u.y);
        acc[4] += blo(u.z); acc[5] += bhi(u.z);
        acc[6] += blo(u.w); acc[7] += bhi(u.w);
    }
    float inv = 1.0f / fmaxf((float)deg, 1.0f);
    uint4 o;
    o.x = ((unsigned)f2b(acc[1] * inv) << 16) | f2b(acc[0] * inv);
    o.y = ((unsigned)f2b(acc[3] * inv) << 16) | f2b(acc[2] * inv);
    o.z = ((unsigned)f2b(acc[5] * inv) << 16) | f2b(acc[4] * inv);
    o.w = ((unsigned)f2b(acc[7] * inv) << 16) | f2b(acc[6] * inv);
    *reinterpret_cast<uint4*>(aggb + (size_t)node * 64 + j * 8) = o;
}

// h = relu([agg | h] @ [wl; wr] + b), in place (bf16 h + bf16 agg, fp32 math).
static __global__ __launch_bounds__(256) void layer_kernel(
        unsigned short* __restrict__ h, const unsigned short* __restrict__ aggb,
        const float* __restrict__ wl, const float* __restrict__ wr,
        const float* __restrict__ b, int n_nodes) {
    __shared__ float inS[64][132];   // [node][k], +4 pad
    __shared__ float wS[128][64];    // [k][col], rows 0..63 = wl, 64..127 = wr
    int t = threadIdx.x;
    int base = blockIdx.x * 64;

    const float4* wl4 = (const float4*)wl;
    const float4* wr4 = (const float4*)wr;
#pragma unroll
    for (int r = 0; r < 4; ++r) {
        int i = t + 256 * r;
        int k = i >> 4, c = (i & 15) * 4;
        *(float4*)&wS[k][c] = wl4[i];
        *(float4*)&wS[64 + k][c] = wr4[i];
    }
#pragma unroll
    for (int r = 0; r < 4; ++r) {
        int i = t + 256 * r;
        int n = i >> 4, c = (i & 15) * 4;
        int node = base + n;
        float4 va = make_float4(0.f, 0.f, 0.f, 0.f);
        float4 vh = make_float4(0.f, 0.f, 0.f, 0.f);
        if (node < n_nodes) {
            va = b4_to_f4(*(const ushort4*)&aggb[(size_t)node * 64 + c]);
            vh = b4_to_f4(*(const ushort4*)&h[(size_t)node * 64 + c]);
        }
        *(float4*)&inS[n][c] = va;
        *(float4*)&inS[n][64 + c] = vh;
    }
    __syncthreads();

    int tx = t & 15, ty = t >> 4;
    int c0 = tx * 4, n0 = ty * 4;
    float4 bias = *(const float4*)&b[c0];
    float acc[4][4];
#pragma unroll
    for (int i = 0; i < 4; ++i) {
        acc[i][0] = bias.x; acc[i][1] = bias.y;
        acc[i][2] = bias.z; acc[i][3] = bias.w;
    }

#pragma unroll 4
    for (int k = 0; k < 128; k += 4) {
        float4 a0 = *(const float4*)&inS[n0 + 0][k];
        float4 a1 = *(const float4*)&inS[n0 + 1][k];
        float4 a2 = *(const float4*)&inS[n0 + 2][k];
        float4 a3 = *(const float4*)&inS[n0 + 3][k];
        float4 w0 = *(const float4*)&wS[k + 0][c0];
        float4 w1 = *(const float4*)&wS[k + 1][c0];
        float4 w2 = *(const float4*)&wS[k + 2][c0];
        float4 w3 = *(const float4*)&wS[k + 3][c0];
#define ROW(i, ai)                                                        \
        acc[i][0] = fmaf(ai.x, w0.x, fmaf(ai.y, w1.x, fmaf(ai.z, w2.x,    \
                    fmaf(ai.w, w3.x, acc[i][0]))));                       \
        acc[i][1] = fmaf(ai.x, w0.y, fmaf(ai.y, w1.y, fmaf(ai.z, w2.y,    \
                    fmaf(ai.w, w3.y, acc[i][1]))));                       \
        acc[i][2] = fmaf(ai.x, w0.z, fmaf(ai.y, w1.z, fmaf(ai.z, w2.z,    \
                    fmaf(ai.w, w3.z, acc[i][2]))));                       \
        acc[i][3] = fmaf(ai.x, w0.w, fmaf(ai.y, w1.w, fmaf(ai.z, w2.w,    \
                    fmaf(ai.w, w3.w, acc[i][3]))));
        ROW(0, a0) ROW(1, a1) ROW(2, a2) ROW(3, a3)
#undef ROW
    }

#pragma unroll
    for (int i = 0; i < 4; ++i) {
        int node = base + n0 + i;
        if (node < n_nodes) {
            ushort4 o;
            o.x = f2b(fmaxf(acc[i][0], 0.f));
            o.y = f2b(fmaxf(acc[i][1], 0.f));
            o.z = f2b(fmaxf(acc[i][2], 0.f));
            o.w = f2b(fmaxf(acc[i][3], 0.f));
            *(ushort4*)&h[(size_t)node * 64 + c0] = o;
        }
    }
}

// batch is sorted: binary-search [start,end) per graph; mean-pool then classify.
static __global__ __launch_bounds__(256) void pool_classify_kernel(
        const unsigned short* __restrict__ h, const int* __restrict__ batch,
        const float* __restrict__ wc, const float* __restrict__ bc,
        void* __restrict__ out, const void* probe, int n_nodes) {
    int f32 = detect_f32(probe, 1024);
    int g = blockIdx.x;
    int t = threadIdx.x;
    int lo = 0, hi = n_nodes;
    while (lo < hi) { int mid = (lo + hi) >> 1; if (batch[mid] < g) lo = mid + 1; else hi = mid; }
    int start = lo;
    hi = n_nodes;
    while (lo < hi) { int mid = (lo + hi) >> 1; if (batch[mid] < g + 1) lo = mid + 1; else hi = mid; }
    int end = lo;

    int r = t >> 6, o = t & 63;
    float partial = 0.0f;
    for (int n = start + r; n < end; n += 4) partial += b2f(h[(size_t)n * 64 + o]);
    __shared__ float sred[4][64];
    __shared__ float pooled[64];
    sred[r][o] = partial;
    __syncthreads();
    if (r == 0) {
        float cntf = fmaxf((float)(end - start), 1.0f);
        pooled[o] = (sred[0][o] + sred[1][o] + sred[2][o] + sred[3][o]) / cntf;
    }
    __syncthreads();
    if (t < 10) {
        float acc = bc[t];
#pragma unroll
        for (int k = 0; k < 64; ++k)
            acc = fmaf(pooled[k], wc[k * 10 + t], acc);
        if (f32) ((float*)out)[g * 10 + t] = acc;
        else     ((__hip_bfloat16*)out)[g * 10 + t] = __float2bfloat16(acc);
    }
}

extern "C" void kernel_launch(void* const* d_in, const int* in_sizes, int n_in,
                              void* d_out, int out_size, void* d_ws, size_t ws_size,
                              hipStream_t stream) {
    const int* x          = (const int*)d_in[0];
    const int* edge_index = (const int*)d_in[1];
    const int* batch      = (const int*)d_in[2];

    const int N = in_sizes[2];        // N_NODES
    const int E = in_sizes[1] / 2;    // edge_index is (2, E)
    const int G = out_size / 10;      // num_graphs

    const int NBE = (E + 4095) / 4096;          // edge tiles
    const int Hsz = 512 * NBE;                  // histogram matrix size
    const int SB  = (Hsz + 511) / 512;          // scanA blocks (<=1024)
    const int MB  = (N * 16 + 255) / 256;       // embed blocks

    // workspace layout
    unsigned short* h    = (unsigned short*)d_ws;           // N*64 bf16
    unsigned short* aggb = h + (size_t)N * 64;              // N*64 bf16
    unsigned* rec   = (unsigned*)(aggb + (size_t)N * 64);   // E packed
    int*   startA  = (int*)(rec + E);                       // N
    int*   cntA    = startA + N;                            // N
    int*   H       = cntA + N;                              // Hsz
    int*   B       = H + Hsz;                               // Hsz
    int*   tmpS    = B + Hsz;                               // Hsz
    int*   bsumS   = tmpS + Hsz;                            // SB (<=1024)
    unsigned* csr_packed = (unsigned*)(bsumS + 1024);       // E: (code<<17)|src
    unsigned short* code = (unsigned short*)(csr_packed + E); // N (padded to 4B)
    float* wbuf    = (float*)(code + (((size_t)N + 1) & ~(size_t)1));

    WParams wp;
    int off = 0;
    for (int i = 0; i < 10; ++i) {
        wp.p[i] = d_in[4 + i];
        wp.off[i] = off;
        off += in_sizes[4 + i];
    }
    wp.off[10] = off;
    const int wtotal = off;

    float* semb_f = wbuf + wp.off[0];
    float* cemb_f = wbuf + wp.off[1];
    float* w1l_f  = wbuf + wp.off[2];
    float* w1r_f  = wbuf + wp.off[3];
    float* b1_f   = wbuf + wp.off[4];
    float* w2l_f  = wbuf + wp.off[5];
    float* w2r_f  = wbuf + wp.off[6];
    float* b2_f   = wbuf + wp.off[7];
    float* wc_f   = wbuf + wp.off[8];
    float* bc_f   = wbuf + wp.off[9];

    const int* src = edge_index;
    const int* tgt = edge_index + E;

    convert_kernel<<<(wtotal + 255) / 256, 256, 0, stream>>>(wp, d_in[4], wbuf, wtotal);

    // CSR build by counting sort (no global returning atomics, no memset)
    hist1_embed_kernel<<<NBE + MB, 256, 0, stream>>>(tgt, H, NBE, x, semb_f,
                                                     cemb_f, h, code, N, E);
    scanA_kernel<<<SB, 256, 0, stream>>>(H, tmpS, bsumS, Hsz);
    scan2_kernel<<<1, 1024, 0, stream>>>(bsumS, SB);
    scanC_kernel<<<(Hsz + 255) / 256, 256, 0, stream>>>(tmpS, bsumS, H, B, Hsz);
    scatter1_kernel<<<NBE, 256, 0, stream>>>(src, tgt, B, rec, NBE, E);
    csr2_kernel<<<512, 256, 0, stream>>>(rec, B, NBE, code, csr_packed,
                                         startA, cntA, N, E);

    // layer 1 (gather from LDS embedding table)
    gather1_kernel<<<(N * 8 + 255) / 256, 256, 0, stream>>>(semb_f, cemb_f,
                                                            startA, cntA,
                                                            csr_packed, aggb, N);
    layer_kernel<<<(N + 63) / 64, 256, 0, stream>>>(h, aggb, w1l_f, w1r_f, b1_f, N);

    // layer 2
    gather_kernel<<<(N * 8 + 255) / 256, 256, 0, stream>>>(h, startA, cntA,
                                                           csr_packed, aggb, N);
    layer_kernel<<<(N + 63) / 64, 256, 0, stream>>>(h, aggb, w2l_f, w2r_f, b2_f, N);

    // pool + classify
    pool_classify_kernel<<<G, 256, 0, stream>>>(h, batch, wc_f, bc_f, d_out, d_in[4], N);
}

// Round 3
// 277.688 us; speedup vs baseline: 1.0840x; 1.0024x over previous
//
#include <hip/hip_runtime.h>
#include <hip/hip_bf16.h>

// SPRGraphNet: embed -> 2x SAGEConv(mean) -> mean-pool per graph -> linear(64->10)
// Inputs detected fp32 (round 2). bf16 h (round 8). Sort-based CSR (round 10).
// Round 16: group-per-node gather (8 lanes/node, no shfl reduce).
// Round 17: layer-1 gather via LDS embedding table (1024 distinct rows).
// Round 18: (a) embed pass -> code pass only (h no longer materialized before
// layer 1; saves 12.8MB write + 12.8MB read); (b) gather1 FUSED into layer1,
// agg kept fp32 in LDS (kills 25.6MB aggb round-trip + 1 launch; self term
// from LDS table = identical bf16 values); (c) scan2 folded into scanC
// (per-block strided sum of raw bsum). 10 launches (was 12).
// gather2/layer2 untouched (gather2 is latency-bound; fusion would cut its
// occupancy -- separate experiment).
// Harness poison fills (~84us/iter at 81% HBM peak) = floor.

struct WParams {
    const void* p[10];
    int off[11];
};

__device__ __forceinline__ float b2f(unsigned short u) {
    return __uint_as_float(((unsigned)u) << 16);
}
__device__ __forceinline__ unsigned short f2b(float f) {
    unsigned x = __float_as_uint(f);
    return (unsigned short)((x + 0x7fff + ((x >> 16) & 1)) >> 16);   // RNE
}
__device__ __forceinline__ float4 b4_to_f4(ushort4 u) {
    return make_float4(b2f(u.x), b2f(u.y), b2f(u.z), b2f(u.w));
}
__device__ __forceinline__ float blo(unsigned u) {   // low bf16 of a dword
    return __uint_as_float(u << 16);
}
__device__ __forceinline__ float bhi(unsigned u) {   // high bf16 of a dword
    return __uint_as_float(u & 0xffff0000u);
}

// Inline dtype detection: fp32 data read as bf16 shows |v|>100 / NaN.
__device__ __forceinline__ int detect_f32(const void* probe, int n_bf16) {
    __shared__ int bad;
    if (threadIdx.x == 0) bad = 0;
    __syncthreads();
    const __hip_bfloat16* p = (const __hip_bfloat16*)probe;
    int lbad = 0;
    for (int i = threadIdx.x; i < n_bf16; i += blockDim.x) {
        float v = __bfloat162float(p[i]);
        if (!(fabsf(v) <= 100.0f)) lbad = 1;
    }
    if (lbad) atomicOr(&bad, 1);
    __syncthreads();
    return bad;
}

__device__ __forceinline__ float loadf(const void* p, int i, int f32) {
    return f32 ? ((const float*)p)[i]
               : __bfloat162float(((const __hip_bfloat16*)p)[i]);
}

static __global__ void convert_kernel(WParams wp, const void* probe,
                                      float* __restrict__ dst, int total) {
    int f32 = detect_f32(probe, 1024);
    int gid = blockIdx.x * blockDim.x + threadIdx.x;
    if (gid >= total) return;
    int s = 0;
    while (gid >= wp.off[s + 1]) ++s;
    dst[gid] = loadf(wp.p[s], gid - wp.off[s], f32);
}

// Blocks [0,NBE): LDS histogram of tgt&511 over a 4096-edge tile -> H[bin][blk].
// Blocks [NBE,..): code[node] = x0*16+x1 (no h materialization; round 18).
static __global__ __launch_bounds__(256) void hist1_code_kernel(
        const int* __restrict__ tgt, int* __restrict__ H, int NBE,
        const int* __restrict__ x, unsigned short* __restrict__ code,
        int n_nodes, int n_edges) {
    if (blockIdx.x < (unsigned)NBE) {
        __shared__ int lh[512];
        int t = threadIdx.x;
        lh[t] = 0; lh[t + 256] = 0;
        __syncthreads();
        int base = blockIdx.x * 4096;              // multiple of 4
        const int4* tgt4 = (const int4*)tgt + (base >> 2);
#pragma unroll
        for (int r = 0; r < 4; ++r) {
            int i4 = t + 256 * r;
            int e = base + i4 * 4;
            if (e + 3 < n_edges) {
                int4 v = tgt4[i4];
                atomicAdd(&lh[v.x & 511], 1);
                atomicAdd(&lh[v.y & 511], 1);
                atomicAdd(&lh[v.z & 511], 1);
                atomicAdd(&lh[v.w & 511], 1);
            } else {
                for (int q = 0; q < 4; ++q) {
                    int ee = e + q;
                    if (ee < n_edges) atomicAdd(&lh[tgt[ee] & 511], 1);
                }
            }
        }
        __syncthreads();
        H[(size_t)t * NBE + blockIdx.x] = lh[t];
        H[(size_t)(t + 256) * NBE + blockIdx.x] = lh[t + 256];
    } else {
        int node = (blockIdx.x - NBE) * 256 + threadIdx.x;
        if (node >= n_nodes) return;
        int2 xv = *(const int2*)&x[node * 2];
        code[node] = (unsigned short)(xv.x * 16 + xv.y);
    }
}

// scanA: 512 elements per block (2/thread), block-inclusive -> tmp, sums -> bsum.
static __global__ __launch_bounds__(256) void scanA_kernel(
        const int* __restrict__ in, int* __restrict__ tmp,
        int* __restrict__ bsum, int n) {
    __shared__ int s[256];
    int t = threadIdx.x;
    int i0 = blockIdx.x * 512 + 2 * t;
    int a0 = (i0 < n) ? in[i0] : 0;
    int a1 = (i0 + 1 < n) ? in[i0 + 1] : 0;
    s[t] = a0 + a1;
    __syncthreads();
#pragma unroll
    for (int d = 1; d < 256; d <<= 1) {
        int x = (t >= d) ? s[t - d] : 0;
        __syncthreads();
        s[t] += x;
        __syncthreads();
    }
    if (i0 < n) tmp[i0] = s[t] - a1;          // inclusive at i0
    if (i0 + 1 < n) tmp[i0 + 1] = s[t];       // inclusive at i0+1
    if (t == 255) bsum[blockIdx.x] = s[255];
}

// scanC (round 18: scan2 folded in): basep = sum of raw bsum[0..blk) computed
// per block by strided sum + LDS reduce; B[i] = tmp[i] + basep - H[i].
static __global__ __launch_bounds__(256) void scanC_kernel(
        const int* __restrict__ tmp, const int* __restrict__ bsum,
        const int* __restrict__ H, int* __restrict__ B, int n) {
    __shared__ int red[256];
    int t = threadIdx.x;
    int blk = blockIdx.x >> 1;        // 512-element scan block (constant/block)
    int partial = 0;
    for (int i = t; i < blk; i += 256) partial += bsum[i];
    red[t] = partial;
    __syncthreads();
#pragma unroll
    for (int d = 128; d > 0; d >>= 1) {
        if (t < d) red[t] += red[t + d];
        __syncthreads();
    }
    int basep = red[0];
    int i = blockIdx.x * 256 + t;
    if (i < n) B[i] = tmp[i] + basep - H[i];
}

// scatter1: re-read tile; LDS cursors seeded from B give global slots directly.
// Write packed 32-bit records ((tgt>>9)<<17 | src) grouped by bucket.
static __global__ __launch_bounds__(256) void scatter1_kernel(
        const int* __restrict__ src, const int* __restrict__ tgt,
        const int* __restrict__ B, unsigned* __restrict__ rec,
        int NBE, int n_edges) {
    __shared__ int cur[512];
    int t = threadIdx.x;
    cur[t]       = B[(size_t)t * NBE + blockIdx.x];
    cur[t + 256] = B[(size_t)(t + 256) * NBE + blockIdx.x];
    __syncthreads();
    int base = blockIdx.x * 4096;
    const int4* tgt4 = (const int4*)tgt + (base >> 2);
    const int4* src4 = (const int4*)src + (base >> 2);
#pragma unroll
    for (int r = 0; r < 4; ++r) {
        int i4 = t + 256 * r;
        int e = base + i4 * 4;
        if (e + 3 < n_edges) {
            int4 tv = tgt4[i4];
            int4 sv = src4[i4];
            int p0 = atomicAdd(&cur[tv.x & 511], 1);
            rec[p0] = ((unsigned)(tv.x >> 9) << 17) | (unsigned)sv.x;
            int p1 = atomicAdd(&cur[tv.y & 511], 1);
            rec[p1] = ((unsigned)(tv.y >> 9) << 17) | (unsigned)sv.y;
            int p2 = atomicAdd(&cur[tv.z & 511], 1);
            rec[p2] = ((unsigned)(tv.z >> 9) << 17) | (unsigned)sv.z;
            int p3 = atomicAdd(&cur[tv.w & 511], 1);
            rec[p3] = ((unsigned)(tv.w >> 9) << 17) | (unsigned)sv.w;
        } else {
            for (int q = 0; q < 4; ++q) {
                int ee = e + q;
                if (ee < n_edges) {
                    int tg = tgt[ee];
                    int pos = atomicAdd(&cur[tg & 511], 1);
                    rec[pos] = ((unsigned)(tg >> 9) << 17) | (unsigned)src[ee];
                }
            }
        }
    }
}

// csr2: one block per bucket b. Records [B[b*NBE], next) share tgt&511==b;
// q = rec>>17 (<196), node = b + (q<<9). LDS hist+scan -> start/cnt + scatter.
// Emits packed (code[src]<<17)|src so gathers need no node lookup.
static __global__ __launch_bounds__(256) void csr2_kernel(
        const unsigned* __restrict__ rec, const int* __restrict__ B,
        int NBE, const unsigned short* __restrict__ code,
        unsigned* __restrict__ csr_packed,
        int* __restrict__ startA, int* __restrict__ cntA,
        int n_nodes, int n_edges) {
    __shared__ int hist[256], scn[256], cursor[256];
    __shared__ int sbeg, send;
    int b = blockIdx.x;
    int t = threadIdx.x;
    hist[t] = 0;
    if (t == 0) {
        sbeg = B[(size_t)b * NBE];
        send = (b == 511) ? n_edges : B[(size_t)(b + 1) * NBE];
    }
    __syncthreads();
    int beg = sbeg, end = send;
    for (int i = beg + t; i < end; i += 256) {
        atomicAdd(&hist[rec[i] >> 17], 1);
    }
    __syncthreads();
    scn[t] = hist[t];
    __syncthreads();
#pragma unroll
    for (int d = 1; d < 256; d <<= 1) {
        int x = (t >= d) ? scn[t - d] : 0;
        __syncthreads();
        scn[t] += x;
        __syncthreads();
    }
    int excl = scn[t] - hist[t];
    cursor[t] = beg + excl;
    int n = b + (t << 9);
    if (n < n_nodes) { startA[n] = beg + excl; cntA[n] = hist[t]; }
    __syncthreads();
    for (int i = beg + t; i < end; i += 256) {
        unsigned r = rec[i];
        unsigned s = r & 0x1FFFFu;
        unsigned cd = code[s];                 // 200KB table, L2-resident
        int p = atomicAdd(&cursor[r >> 17], 1);
        csr_packed[p] = (cd << 17) | s;
    }
}

// Round 18: fused layer 1. Per 64-node block:
//   stage: sT/cT (packed bf16 emb tables), wS (fp32 weights), codes.
//   gather phase: 32 groups x 8 lanes, 2 nodes/group; LDS table rows; agg
//     written fp32 to inS[n][0..64) (no bf16 round-trip).
//   self phase: inS[n][64..128) from table row of code[n] (identical bf16
//     values to the old embed pass).
//   GEMM phase: identical to layer_kernel; writes h bf16.
static __global__ __launch_bounds__(256) void layer1_fused_kernel(
        const float* __restrict__ semb, const float* __restrict__ cemb,
        const unsigned short* __restrict__ code,
        const int* __restrict__ startA, const int* __restrict__ cntA,
        const unsigned* __restrict__ csr_packed,
        const float* __restrict__ wl, const float* __restrict__ wr,
        const float* __restrict__ b,
        unsigned short* __restrict__ h, int n_nodes) {
    __shared__ __align__(16) unsigned sT[64 * 20];   // 5120B
    __shared__ __align__(16) unsigned cT[16 * 20];   // 1280B
    __shared__ float inS[64][132];   // [node][k]: 0..63 agg (fp32), 64..127 self
    __shared__ float wS[128][64];    // rows 0..63 = wl, 64..127 = wr
    __shared__ unsigned short codeL[64];
    int t = threadIdx.x;
    int base = blockIdx.x * 64;

    for (int i = t; i < 64 * 16; i += 256) {
        int r = i >> 4, c = i & 15;
        float lo = semb[r * 32 + c * 2], hi = semb[r * 32 + c * 2 + 1];
        sT[r * 20 + c] = ((unsigned)f2b(hi) << 16) | f2b(lo);
    }
    for (int i = t; i < 16 * 16; i += 256) {
        int r = i >> 4, c = i & 15;
        float lo = cemb[r * 32 + c * 2], hi = cemb[r * 32 + c * 2 + 1];
        cT[r * 20 + c] = ((unsigned)f2b(hi) << 16) | f2b(lo);
    }
    const float4* wl4 = (const float4*)wl;
    const float4* wr4 = (const float4*)wr;
#pragma unroll
    for (int r = 0; r < 4; ++r) {
        int i = t + 256 * r;
        int k = i >> 4, c = (i & 15) * 4;
        *(float4*)&wS[k][c] = wl4[i];
        *(float4*)&wS[64 + k][c] = wr4[i];
    }
    if (t < 64) {
        int node = base + t;
        codeL[t] = (node < n_nodes) ? code[node] : 0;
    }
    __syncthreads();

    // ---- gather phase (agg, fp32) ----
    {
        int g = t >> 3, j = t & 7;
        const uint4* sT4 = (const uint4*)sT;     // row = 5 uint4
        const uint4* cT4 = (const uint4*)cT;
        int js = j, jc = j - 4;
#pragma unroll
        for (int half = 0; half < 2; ++half) {
            int n = g + half * 32;
            int node = base + n;
            float acc[8];
#pragma unroll
            for (int k = 0; k < 8; ++k) acc[k] = 0.f;
            float inv = 1.0f;
            if (node < n_nodes) {
                int beg = startA[node], deg = cntA[node];
                int it = 0;
                for (; it + 1 < deg; it += 2) {
                    unsigned p0 = csr_packed[beg + it];
                    unsigned p1 = csr_packed[beg + it + 1];
                    unsigned c0 = p0 >> 17, c1 = p1 >> 17;
                    const uint4* a0 = (j < 4) ? sT4 + (c0 >> 4) * 5 + js
                                              : cT4 + (c0 & 15) * 5 + jc;
                    const uint4* a1 = (j < 4) ? sT4 + (c1 >> 4) * 5 + js
                                              : cT4 + (c1 & 15) * 5 + jc;
                    uint4 u0 = *a0;
                    uint4 u1 = *a1;
                    acc[0] += blo(u0.x) + blo(u1.x);
                    acc[1] += bhi(u0.x) + bhi(u1.x);
                    acc[2] += blo(u0.y) + blo(u1.y);
                    acc[3] += bhi(u0.y) + bhi(u1.y);
                    acc[4] += blo(u0.z) + blo(u1.z);
                    acc[5] += bhi(u0.z) + bhi(u1.z);
                    acc[6] += blo(u0.w) + blo(u1.w);
                    acc[7] += bhi(u0.w) + bhi(u1.w);
                }
                if (it < deg) {
                    unsigned p0 = csr_packed[beg + it];
                    unsigned c0 = p0 >> 17;
                    const uint4* a0 = (j < 4) ? sT4 + (c0 >> 4) * 5 + js
                                              : cT4 + (c0 & 15) * 5 + jc;
                    uint4 u = *a0;
                    acc[0] += blo(u.x); acc[1] += bhi(u.x);
                    acc[2] += blo(u.y); acc[3] += bhi(u.y);
                    acc[4] += blo(u.z); acc[5] += bhi(u.z);
                    acc[6] += blo(u.w); acc[7] += bhi(u.w);
                }
                inv = 1.0f / fmaxf((float)deg, 1.0f);
            }
            *(float4*)&inS[n][j * 8] =
                make_float4(acc[0] * inv, acc[1] * inv, acc[2] * inv, acc[3] * inv);
            *(float4*)&inS[n][j * 8 + 4] =
                make_float4(acc[4] * inv, acc[5] * inv, acc[6] * inv, acc[7] * inv);
        }
    }

    // ---- self phase (table row of code[n], identical bf16 values) ----
    for (int i = t; i < 64 * 16; i += 256) {
        int n = i >> 4, c4 = (i & 15) * 4;     // c4 in {0,4,...,60}
        unsigned cd = codeL[n];
        unsigned u0, u1;
        if (c4 < 32) {
            int idx = (cd >> 4) * 20 + (c4 >> 1);
            u0 = sT[idx]; u1 = sT[idx + 1];
        } else {
            int idx = (cd & 15) * 20 + ((c4 - 32) >> 1);
            u0 = cT[idx]; u1 = cT[idx + 1];
        }
        inS[n][64 + c4]     = blo(u0);
        inS[n][64 + c4 + 1] = bhi(u0);
        inS[n][64 + c4 + 2] = blo(u1);
        inS[n][64 + c4 + 3] = bhi(u1);
    }
    __syncthreads();

    // ---- GEMM phase ----
    int tx = t & 15, ty = t >> 4;
    int c0 = tx * 4, n0 = ty * 4;
    float4 bias = *(const float4*)&b[c0];
    float acc[4][4];
#pragma unroll
    for (int i = 0; i < 4; ++i) {
        acc[i][0] = bias.x; acc[i][1] = bias.y;
        acc[i][2] = bias.z; acc[i][3] = bias.w;
    }

#pragma unroll 4
    for (int k = 0; k < 128; k += 4) {
        float4 a0 = *(const float4*)&inS[n0 + 0][k];
        float4 a1 = *(const float4*)&inS[n0 + 1][k];
        float4 a2 = *(const float4*)&inS[n0 + 2][k];
        float4 a3 = *(const float4*)&inS[n0 + 3][k];
        float4 w0 = *(const float4*)&wS[k + 0][c0];
        float4 w1 = *(const float4*)&wS[k + 1][c0];
        float4 w2 = *(const float4*)&wS[k + 2][c0];
        float4 w3 = *(const float4*)&wS[k + 3][c0];
#define ROW(i, ai)                                                        \
        acc[i][0] = fmaf(ai.x, w0.x, fmaf(ai.y, w1.x, fmaf(ai.z, w2.x,    \
                    fmaf(ai.w, w3.x, acc[i][0]))));                       \
        acc[i][1] = fmaf(ai.x, w0.y, fmaf(ai.y, w1.y, fmaf(ai.z, w2.y,    \
                    fmaf(ai.w, w3.y, acc[i][1]))));                       \
        acc[i][2] = fmaf(ai.x, w0.z, fmaf(ai.y, w1.z, fmaf(ai.z, w2.z,    \
                    fmaf(ai.w, w3.z, acc[i][2]))));                       \
        acc[i][3] = fmaf(ai.x, w0.w, fmaf(ai.y, w1.w, fmaf(ai.z, w2.w,    \
                    fmaf(ai.w, w3.w, acc[i][3]))));
        ROW(0, a0) ROW(1, a1) ROW(2, a2) ROW(3, a3)
#undef ROW
    }

#pragma unroll
    for (int i = 0; i < 4; ++i) {
        int node = base + n0 + i;
        if (node < n_nodes) {
            ushort4 o;
            o.x = f2b(fmaxf(acc[i][0], 0.f));
            o.y = f2b(fmaxf(acc[i][1], 0.f));
            o.z = f2b(fmaxf(acc[i][2], 0.f));
            o.w = f2b(fmaxf(acc[i][3], 0.f));
            *(ushort4*)&h[(size_t)node * 64 + c0] = o;
        }
    }
}

// Round 16 gather (layer 2): group-per-node, 8 lanes/node, lane j cols [8j,8j+8).
static __global__ __launch_bounds__(256) void gather_kernel(
        const unsigned short* __restrict__ h, const int* __restrict__ startA,
        const int* __restrict__ cntA,
        const unsigned* __restrict__ csr_packed, unsigned short* __restrict__ aggb,
        int n_nodes) {
    int node = (blockIdx.x * 256 + threadIdx.x) >> 3;
    int j = threadIdx.x & 7;                 // cols [8j, 8j+8)
    if (node >= n_nodes) return;
    int beg = startA[node], deg = cntA[node];

    float acc[8];
#pragma unroll
    for (int k = 0; k < 8; ++k) acc[k] = 0.f;

    const unsigned short* hj = h + j * 8;
    int it = 0;
    for (; it + 1 < deg; it += 2) {
        int s0 = (int)(csr_packed[beg + it] & 0x1FFFFu);
        int s1 = (int)(csr_packed[beg + it + 1] & 0x1FFFFu);
        uint4 u0 = *reinterpret_cast<const uint4*>(hj + (size_t)s0 * 64);
        uint4 u1 = *reinterpret_cast<const uint4*>(hj + (size_t)s1 * 64);
        acc[0] += blo(u0.x) + blo(u1.x);
        acc[1] += bhi(u0.x) + bhi(u1.x);
        acc[2] += blo(u0.y) + blo(u1.y);
        acc[3] += bhi(u0.y) + bhi(u1.y);
        acc[4] += blo(u0.z) + blo(u1.z);
        acc[5] += bhi(u0.z) + bhi(u1.z);
        acc[6] += blo(u0.w) + blo(u1.w);
        acc[7] += bhi(u0.w) + bhi(u1.w);
    }
    if (it < deg) {
        int s = (int)(csr_packed[beg + it] & 0x1FFFFu);
        uint4 u = *reinterpret_cast<const uint4*>(hj + (size_t)s * 64);
        acc[0] += blo(u.x); acc[1] += bhi(u.x);
        acc[2] += blo(u.y); acc[3] += bhi(u.y);
        acc[4] += blo(u.z); acc[5] += bhi(u.z);
        acc[6] += blo(u.w); acc[7] += bhi(u.w);
    }
    float inv = 1.0f / fmaxf((float)deg, 1.0f);
    uint4 o;
    o.x = ((unsigned)f2b(acc[1] * inv) << 16) | f2b(acc[0] * inv);
    o.y = ((unsigned)f2b(acc[3] * inv) << 16) | f2b(acc[2] * inv);
    o.z = ((unsigned)f2b(acc[5] * inv) << 16) | f2b(acc[4] * inv);
    o.w = ((unsigned)f2b(acc[7] * inv) << 16) | f2b(acc[6] * inv);
    *reinterpret_cast<uint4*>(aggb + (size_t)node * 64 + j * 8) = o;
}

// h = relu([agg | h] @ [wl; wr] + b), in place (bf16 h + bf16 agg, fp32 math).
static __global__ __launch_bounds__(256) void layer_kernel(
        unsigned short* __restrict__ h, const unsigned short* __restrict__ aggb,
        const float* __restrict__ wl, const float* __restrict__ wr,
        const float* __restrict__ b, int n_nodes) {
    __shared__ float inS[64][132];   // [node][k], +4 pad
    __shared__ float wS[128][64];    // [k][col], rows 0..63 = wl, 64..127 = wr
    int t = threadIdx.x;
    int base = blockIdx.x * 64;

    const float4* wl4 = (const float4*)wl;
    const float4* wr4 = (const float4*)wr;
#pragma unroll
    for (int r = 0; r < 4; ++r) {
        int i = t + 256 * r;
        int k = i >> 4, c = (i & 15) * 4;
        *(float4*)&wS[k][c] = wl4[i];
        *(float4*)&wS[64 + k][c] = wr4[i];
    }
#pragma unroll
    for (int r = 0; r < 4; ++r) {
        int i = t + 256 * r;
        int n = i >> 4, c = (i & 15) * 4;
        int node = base + n;
        float4 va = make_float4(0.f, 0.f, 0.f, 0.f);
        float4 vh = make_float4(0.f, 0.f, 0.f, 0.f);
        if (node < n_nodes) {
            va = b4_to_f4(*(const ushort4*)&aggb[(size_t)node * 64 + c]);
            vh = b4_to_f4(*(const ushort4*)&h[(size_t)node * 64 + c]);
        }
        *(float4*)&inS[n][c] = va;
        *(float4*)&inS[n][64 + c] = vh;
    }
    __syncthreads();

    int tx = t & 15, ty = t >> 4;
    int c0 = tx * 4, n0 = ty * 4;
    float4 bias = *(const float4*)&b[c0];
    float acc[4][4];
#pragma unroll
    for (int i = 0; i < 4; ++i) {
        acc[i][0] = bias.x; acc[i][1] = bias.y;
        acc[i][2] = bias.z; acc[i][3] = bias.w;
    }

#pragma unroll 4
    for (int k = 0; k < 128; k += 4) {
        float4 a0 = *(const float4*)&inS[n0 + 0][k];
        float4 a1 = *(const float4*)&inS[n0 + 1][k];
        float4 a2 = *(const float4*)&inS[n0 + 2][k];
        float4 a3 = *(const float4*)&inS[n0 + 3][k];
        float4 w0 = *(const float4*)&wS[k + 0][c0];
        float4 w1 = *(const float4*)&wS[k + 1][c0];
        float4 w2 = *(const float4*)&wS[k + 2][c0];
        float4 w3 = *(const float4*)&wS[k + 3][c0];
#define ROW(i, ai)                                                        \
        acc[i][0] = fmaf(ai.x, w0.x, fmaf(ai.y, w1.x, fmaf(ai.z, w2.x,    \
                    fmaf(ai.w, w3.x, acc[i][0]))));                       \
        acc[i][1] = fmaf(ai.x, w0.y, fmaf(ai.y, w1.y, fmaf(ai.z, w2.y,    \
                    fmaf(ai.w, w3.y, acc[i][1]))));                       \
        acc[i][2] = fmaf(ai.x, w0.z, fmaf(ai.y, w1.z, fmaf(ai.z, w2.z,    \
                    fmaf(ai.w, w3.z, acc[i][2]))));                       \
        acc[i][3] = fmaf(ai.x, w0.w, fmaf(ai.y, w1.w, fmaf(ai.z, w2.w,    \
                    fmaf(ai.w, w3.w, acc[i][3]))));
        ROW(0, a0) ROW(1, a1) ROW(2, a2) ROW(3, a3)
#undef ROW
    }

#pragma unroll
    for (int i = 0; i < 4; ++i) {
        int node = base + n0 + i;
        if (node < n_nodes) {
            ushort4 o;
            o.x = f2b(fmaxf(acc[i][0], 0.f));
            o.y = f2b(fmaxf(acc[i][1], 0.f));
            o.z = f2b(fmaxf(acc[i][2], 0.f));
            o.w = f2b(fmaxf(acc[i][3], 0.f));
            *(ushort4*)&h[(size_t)node * 64 + c0] = o;
        }
    }
}

// batch is sorted: binary-search [start,end) per graph; mean-pool then classify.
static __global__ __launch_bounds__(256) void pool_classify_kernel(
        const unsigned short* __restrict__ h, const int* __restrict__ batch,
        const float* __restrict__ wc, const float* __restrict__ bc,
        void* __restrict__ out, const void* probe, int n_nodes) {
    int f32 = detect_f32(probe, 1024);
    int g = blockIdx.x;
    int t = threadIdx.x;
    int lo = 0, hi = n_nodes;
    while (lo < hi) { int mid = (lo + hi) >> 1; if (batch[mid] < g) lo = mid + 1; else hi = mid; }
    int start = lo;
    hi = n_nodes;
    while (lo < hi) { int mid = (lo + hi) >> 1; if (batch[mid] < g + 1) lo = mid + 1; else hi = mid; }
    int end = lo;

    int r = t >> 6, o = t & 63;
    float partial = 0.0f;
    for (int n = start + r; n < end; n += 4) partial += b2f(h[(size_t)n * 64 + o]);
    __shared__ float sred[4][64];
    __shared__ float pooled[64];
    sred[r][o] = partial;
    __syncthreads();
    if (r == 0) {
        float cntf = fmaxf((float)(end - start), 1.0f);
        pooled[o] = (sred[0][o] + sred[1][o] + sred[2][o] + sred[3][o]) / cntf;
    }
    __syncthreads();
    if (t < 10) {
        float acc = bc[t];
#pragma unroll
        for (int k = 0; k < 64; ++k)
            acc = fmaf(pooled[k], wc[k * 10 + t], acc);
        if (f32) ((float*)out)[g * 10 + t] = acc;
        else     ((__hip_bfloat16*)out)[g * 10 + t] = __float2bfloat16(acc);
    }
}

extern "C" void kernel_launch(void* const* d_in, const int* in_sizes, int n_in,
                              void* d_out, int out_size, void* d_ws, size_t ws_size,
                              hipStream_t stream) {
    const int* x          = (const int*)d_in[0];
    const int* edge_index = (const int*)d_in[1];
    const int* batch      = (const int*)d_in[2];

    const int N = in_sizes[2];        // N_NODES
    const int E = in_sizes[1] / 2;    // edge_index is (2, E)
    const int G = out_size / 10;      // num_graphs

    const int NBE = (E + 4095) / 4096;          // edge tiles
    const int Hsz = 512 * NBE;                  // histogram matrix size
    const int SB  = (Hsz + 511) / 512;          // scanA blocks (<=1024)
    const int CB  = (N + 255) / 256;            // code blocks

    // workspace layout
    unsigned short* h    = (unsigned short*)d_ws;           // N*64 bf16
    unsigned short* aggb = h + (size_t)N * 64;              // N*64 bf16
    unsigned* rec   = (unsigned*)(aggb + (size_t)N * 64);   // E packed
    int*   startA  = (int*)(rec + E);                       // N
    int*   cntA    = startA + N;                            // N
    int*   H       = cntA + N;                              // Hsz
    int*   B       = H + Hsz;                               // Hsz
    int*   tmpS    = B + Hsz;                               // Hsz
    int*   bsumS   = tmpS + Hsz;                            // SB (<=1024)
    unsigned* csr_packed = (unsigned*)(bsumS + 1024);       // E: (code<<17)|src
    unsigned short* code = (unsigned short*)(csr_packed + E); // N (padded to 4B)
    float* wbuf    = (float*)(code + (((size_t)N + 1) & ~(size_t)1));

    WParams wp;
    int off = 0;
    for (int i = 0; i < 10; ++i) {
        wp.p[i] = d_in[4 + i];
        wp.off[i] = off;
        off += in_sizes[4 + i];
    }
    wp.off[10] = off;
    const int wtotal = off;

    float* semb_f = wbuf + wp.off[0];
    float* cemb_f = wbuf + wp.off[1];
    float* w1l_f  = wbuf + wp.off[2];
    float* w1r_f  = wbuf + wp.off[3];
    float* b1_f   = wbuf + wp.off[4];
    float* w2l_f  = wbuf + wp.off[5];
    float* w2r_f  = wbuf + wp.off[6];
    float* b2_f   = wbuf + wp.off[7];
    float* wc_f   = wbuf + wp.off[8];
    float* bc_f   = wbuf + wp.off[9];

    const int* src = edge_index;
    const int* tgt = edge_index + E;

    convert_kernel<<<(wtotal + 255) / 256, 256, 0, stream>>>(wp, d_in[4], wbuf, wtotal);

    // CSR build by counting sort (no global returning atomics, no memset)
    hist1_code_kernel<<<NBE + CB, 256, 0, stream>>>(tgt, H, NBE, x, code, N, E);
    scanA_kernel<<<SB, 256, 0, stream>>>(H, tmpS, bsumS, Hsz);
    scanC_kernel<<<(Hsz + 255) / 256, 256, 0, stream>>>(tmpS, bsumS, H, B, Hsz);
    scatter1_kernel<<<NBE, 256, 0, stream>>>(src, tgt, B, rec, NBE, E);
    csr2_kernel<<<512, 256, 0, stream>>>(rec, B, NBE, code, csr_packed,
                                         startA, cntA, N, E);

    // layer 1 (fused gather-from-LDS-table + GEMM; writes h)
    layer1_fused_kernel<<<(N + 63) / 64, 256, 0, stream>>>(
        semb_f, cemb_f, code, startA, cntA, csr_packed,
        w1l_f, w1r_f, b1_f, h, N);

    // layer 2
    gather_kernel<<<(N * 8 + 255) / 256, 256, 0, stream>>>(h, startA, cntA,
                                                           csr_packed, aggb, N);
    layer_kernel<<<(N + 63) / 64, 256, 0, stream>>>(h, aggb, w2l_f, w2r_f, b2_f, N);

    // pool + classify
    pool_classify_kernel<<<G, 256, 0, stream>>>(h, batch, wc_f, bc_f, d_out, d_in[4], N);
}

// Round 4
// 271.671 us; speedup vs baseline: 1.1080x; 1.0221x over previous
//
#include <hip/hip_runtime.h>
#include <hip/hip_bf16.h>

// SPRGraphNet: embed -> 2x SAGEConv(mean) -> mean-pool per graph -> linear(64->10)
// Inputs detected fp32 (round 2). bf16 h (round 8). Sort-based CSR (round 10).
// Round 16: group-per-node gather (8 lanes/node, no shfl reduce).
// Round 17: layer-1 gather via LDS embedding table (1024 distinct rows).
// Round 18: code-only pass (no embed materialization), scan2 folded into scanC.
// Round 19: UN-FUSE gather1 from layer1. R18's fusion dropped the gather phase
// to 2 blocks/CU (73KB LDS) -> latency-bound at 16% occupancy, 62.9us. Lesson:
// gather needs TLP/occupancy; GEMM tolerates low occupancy. Now: standalone
// gather1 (6.4KB LDS table, writes bf16 aggb, high occupancy) + layer1s
// (= layer GEMM, self term from LDS table via code[node] -- keeps R18's
// "no h materialization" win). Identical numerics to r17 (absmax 9.77e-4).
// Harness poison fills (~84us/iter at 81% HBM peak) = floor.

struct WParams {
    const void* p[10];
    int off[11];
};

__device__ __forceinline__ float b2f(unsigned short u) {
    return __uint_as_float(((unsigned)u) << 16);
}
__device__ __forceinline__ unsigned short f2b(float f) {
    unsigned x = __float_as_uint(f);
    return (unsigned short)((x + 0x7fff + ((x >> 16) & 1)) >> 16);   // RNE
}
__device__ __forceinline__ float4 b4_to_f4(ushort4 u) {
    return make_float4(b2f(u.x), b2f(u.y), b2f(u.z), b2f(u.w));
}
__device__ __forceinline__ float blo(unsigned u) {   // low bf16 of a dword
    return __uint_as_float(u << 16);
}
__device__ __forceinline__ float bhi(unsigned u) {   // high bf16 of a dword
    return __uint_as_float(u & 0xffff0000u);
}

// Inline dtype detection: fp32 data read as bf16 shows |v|>100 / NaN.
__device__ __forceinline__ int detect_f32(const void* probe, int n_bf16) {
    __shared__ int bad;
    if (threadIdx.x == 0) bad = 0;
    __syncthreads();
    const __hip_bfloat16* p = (const __hip_bfloat16*)probe;
    int lbad = 0;
    for (int i = threadIdx.x; i < n_bf16; i += blockDim.x) {
        float v = __bfloat162float(p[i]);
        if (!(fabsf(v) <= 100.0f)) lbad = 1;
    }
    if (lbad) atomicOr(&bad, 1);
    __syncthreads();
    return bad;
}

__device__ __forceinline__ float loadf(const void* p, int i, int f32) {
    return f32 ? ((const float*)p)[i]
               : __bfloat162float(((const __hip_bfloat16*)p)[i]);
}

static __global__ void convert_kernel(WParams wp, const void* probe,
                                      float* __restrict__ dst, int total) {
    int f32 = detect_f32(probe, 1024);
    int gid = blockIdx.x * blockDim.x + threadIdx.x;
    if (gid >= total) return;
    int s = 0;
    while (gid >= wp.off[s + 1]) ++s;
    dst[gid] = loadf(wp.p[s], gid - wp.off[s], f32);
}

// Blocks [0,NBE): LDS histogram of tgt&511 over a 4096-edge tile -> H[bin][blk].
// Blocks [NBE,..): code[node] = x0*16+x1.
static __global__ __launch_bounds__(256) void hist1_code_kernel(
        const int* __restrict__ tgt, int* __restrict__ H, int NBE,
        const int* __restrict__ x, unsigned short* __restrict__ code,
        int n_nodes, int n_edges) {
    if (blockIdx.x < (unsigned)NBE) {
        __shared__ int lh[512];
        int t = threadIdx.x;
        lh[t] = 0; lh[t + 256] = 0;
        __syncthreads();
        int base = blockIdx.x * 4096;              // multiple of 4
        const int4* tgt4 = (const int4*)tgt + (base >> 2);
#pragma unroll
        for (int r = 0; r < 4; ++r) {
            int i4 = t + 256 * r;
            int e = base + i4 * 4;
            if (e + 3 < n_edges) {
                int4 v = tgt4[i4];
                atomicAdd(&lh[v.x & 511], 1);
                atomicAdd(&lh[v.y & 511], 1);
                atomicAdd(&lh[v.z & 511], 1);
                atomicAdd(&lh[v.w & 511], 1);
            } else {
                for (int q = 0; q < 4; ++q) {
                    int ee = e + q;
                    if (ee < n_edges) atomicAdd(&lh[tgt[ee] & 511], 1);
                }
            }
        }
        __syncthreads();
        H[(size_t)t * NBE + blockIdx.x] = lh[t];
        H[(size_t)(t + 256) * NBE + blockIdx.x] = lh[t + 256];
    } else {
        int node = (blockIdx.x - NBE) * 256 + threadIdx.x;
        if (node >= n_nodes) return;
        int2 xv = *(const int2*)&x[node * 2];
        code[node] = (unsigned short)(xv.x * 16 + xv.y);
    }
}

// scanA: 512 elements per block (2/thread), block-inclusive -> tmp, sums -> bsum.
static __global__ __launch_bounds__(256) void scanA_kernel(
        const int* __restrict__ in, int* __restrict__ tmp,
        int* __restrict__ bsum, int n) {
    __shared__ int s[256];
    int t = threadIdx.x;
    int i0 = blockIdx.x * 512 + 2 * t;
    int a0 = (i0 < n) ? in[i0] : 0;
    int a1 = (i0 + 1 < n) ? in[i0 + 1] : 0;
    s[t] = a0 + a1;
    __syncthreads();
#pragma unroll
    for (int d = 1; d < 256; d <<= 1) {
        int x = (t >= d) ? s[t - d] : 0;
        __syncthreads();
        s[t] += x;
        __syncthreads();
    }
    if (i0 < n) tmp[i0] = s[t] - a1;          // inclusive at i0
    if (i0 + 1 < n) tmp[i0 + 1] = s[t];       // inclusive at i0+1
    if (t == 255) bsum[blockIdx.x] = s[255];
}

// scanC: basep = sum of raw bsum[0..blk) per block; B[i] = tmp[i]+basep-H[i].
static __global__ __launch_bounds__(256) void scanC_kernel(
        const int* __restrict__ tmp, const int* __restrict__ bsum,
        const int* __restrict__ H, int* __restrict__ B, int n) {
    __shared__ int red[256];
    int t = threadIdx.x;
    int blk = blockIdx.x >> 1;        // 512-element scan block (constant/block)
    int partial = 0;
    for (int i = t; i < blk; i += 256) partial += bsum[i];
    red[t] = partial;
    __syncthreads();
#pragma unroll
    for (int d = 128; d > 0; d >>= 1) {
        if (t < d) red[t] += red[t + d];
        __syncthreads();
    }
    int basep = red[0];
    int i = blockIdx.x * 256 + t;
    if (i < n) B[i] = tmp[i] + basep - H[i];
}

// scatter1: re-read tile; LDS cursors seeded from B give global slots directly.
// Write packed 32-bit records ((tgt>>9)<<17 | src) grouped by bucket.
static __global__ __launch_bounds__(256) void scatter1_kernel(
        const int* __restrict__ src, const int* __restrict__ tgt,
        const int* __restrict__ B, unsigned* __restrict__ rec,
        int NBE, int n_edges) {
    __shared__ int cur[512];
    int t = threadIdx.x;
    cur[t]       = B[(size_t)t * NBE + blockIdx.x];
    cur[t + 256] = B[(size_t)(t + 256) * NBE + blockIdx.x];
    __syncthreads();
    int base = blockIdx.x * 4096;
    const int4* tgt4 = (const int4*)tgt + (base >> 2);
    const int4* src4 = (const int4*)src + (base >> 2);
#pragma unroll
    for (int r = 0; r < 4; ++r) {
        int i4 = t + 256 * r;
        int e = base + i4 * 4;
        if (e + 3 < n_edges) {
            int4 tv = tgt4[i4];
            int4 sv = src4[i4];
            int p0 = atomicAdd(&cur[tv.x & 511], 1);
            rec[p0] = ((unsigned)(tv.x >> 9) << 17) | (unsigned)sv.x;
            int p1 = atomicAdd(&cur[tv.y & 511], 1);
            rec[p1] = ((unsigned)(tv.y >> 9) << 17) | (unsigned)sv.y;
            int p2 = atomicAdd(&cur[tv.z & 511], 1);
            rec[p2] = ((unsigned)(tv.z >> 9) << 17) | (unsigned)sv.z;
            int p3 = atomicAdd(&cur[tv.w & 511], 1);
            rec[p3] = ((unsigned)(tv.w >> 9) << 17) | (unsigned)sv.w;
        } else {
            for (int q = 0; q < 4; ++q) {
                int ee = e + q;
                if (ee < n_edges) {
                    int tg = tgt[ee];
                    int pos = atomicAdd(&cur[tg & 511], 1);
                    rec[pos] = ((unsigned)(tg >> 9) << 17) | (unsigned)src[ee];
                }
            }
        }
    }
}

// csr2: one block per bucket b. Records [B[b*NBE], next) share tgt&511==b;
// q = rec>>17 (<196), node = b + (q<<9). LDS hist+scan -> start/cnt + scatter.
// Emits packed (code[src]<<17)|src so gathers need no node lookup.
static __global__ __launch_bounds__(256) void csr2_kernel(
        const unsigned* __restrict__ rec, const int* __restrict__ B,
        int NBE, const unsigned short* __restrict__ code,
        unsigned* __restrict__ csr_packed,
        int* __restrict__ startA, int* __restrict__ cntA,
        int n_nodes, int n_edges) {
    __shared__ int hist[256], scn[256], cursor[256];
    __shared__ int sbeg, send;
    int b = blockIdx.x;
    int t = threadIdx.x;
    hist[t] = 0;
    if (t == 0) {
        sbeg = B[(size_t)b * NBE];
        send = (b == 511) ? n_edges : B[(size_t)(b + 1) * NBE];
    }
    __syncthreads();
    int beg = sbeg, end = send;
    for (int i = beg + t; i < end; i += 256) {
        atomicAdd(&hist[rec[i] >> 17], 1);
    }
    __syncthreads();
    scn[t] = hist[t];
    __syncthreads();
#pragma unroll
    for (int d = 1; d < 256; d <<= 1) {
        int x = (t >= d) ? scn[t - d] : 0;
        __syncthreads();
        scn[t] += x;
        __syncthreads();
    }
    int excl = scn[t] - hist[t];
    cursor[t] = beg + excl;
    int n = b + (t << 9);
    if (n < n_nodes) { startA[n] = beg + excl; cntA[n] = hist[t]; }
    __syncthreads();
    for (int i = beg + t; i < end; i += 256) {
        unsigned r = rec[i];
        unsigned s = r & 0x1FFFFu;
        unsigned cd = code[s];                 // 200KB table, L2-resident
        int p = atomicAdd(&cursor[r >> 17], 1);
        csr_packed[p] = (cd << 17) | s;
    }
}

// Layer-1 gather from LDS embedding table (r17 version: standalone, high
// occupancy). 8 lanes per node; lane j owns cols [8j,8j+8). Row for code c is
// [semb[c>>4] | cemb[c&15]]: lanes 0-3 read semb LDS, 4-7 read cemb LDS.
// Row stride 20 uints (80B) for bank spread. Writes bf16 aggb.
static __global__ __launch_bounds__(256) void gather1_kernel(
        const float* __restrict__ semb, const float* __restrict__ cemb,
        const int* __restrict__ startA, const int* __restrict__ cntA,
        const unsigned* __restrict__ csr_packed, unsigned short* __restrict__ aggb,
        int n_nodes) {
    __shared__ __align__(16) unsigned sT[64 * 20];   // 5120B
    __shared__ __align__(16) unsigned cT[16 * 20];   // 1280B
    int t = threadIdx.x;
    for (int i = t; i < 64 * 16; i += 256) {
        int r = i >> 4, c = i & 15;
        float lo = semb[r * 32 + c * 2], hi = semb[r * 32 + c * 2 + 1];
        sT[r * 20 + c] = ((unsigned)f2b(hi) << 16) | f2b(lo);
    }
    for (int i = t; i < 16 * 16; i += 256) {
        int r = i >> 4, c = i & 15;
        float lo = cemb[r * 32 + c * 2], hi = cemb[r * 32 + c * 2 + 1];
        cT[r * 20 + c] = ((unsigned)f2b(hi) << 16) | f2b(lo);
    }
    __syncthreads();

    int node = (blockIdx.x * 256 + t) >> 3;
    int j = t & 7;                           // cols [8j, 8j+8)
    if (node >= n_nodes) return;
    int beg = startA[node], deg = cntA[node];

    const uint4* sT4 = (const uint4*)sT;     // row = 5 uint4
    const uint4* cT4 = (const uint4*)cT;
    int js = j, jc = j - 4;                  // lane's block within sub-table

    float acc[8];
#pragma unroll
    for (int k = 0; k < 8; ++k) acc[k] = 0.f;

    int it = 0;
    for (; it + 1 < deg; it += 2) {
        unsigned p0 = csr_packed[beg + it];
        unsigned p1 = csr_packed[beg + it + 1];
        unsigned c0 = p0 >> 17, c1 = p1 >> 17;
        const uint4* a0 = (j < 4) ? sT4 + (c0 >> 4) * 5 + js
                                  : cT4 + (c0 & 15) * 5 + jc;
        const uint4* a1 = (j < 4) ? sT4 + (c1 >> 4) * 5 + js
                                  : cT4 + (c1 & 15) * 5 + jc;
        uint4 u0 = *a0;
        uint4 u1 = *a1;
        acc[0] += blo(u0.x) + blo(u1.x);
        acc[1] += bhi(u0.x) + bhi(u1.x);
        acc[2] += blo(u0.y) + blo(u1.y);
        acc[3] += bhi(u0.y) + bhi(u1.y);
        acc[4] += blo(u0.z) + blo(u1.z);
        acc[5] += bhi(u0.z) + bhi(u1.z);
        acc[6] += blo(u0.w) + blo(u1.w);
        acc[7] += bhi(u0.w) + bhi(u1.w);
    }
    if (it < deg) {
        unsigned p0 = csr_packed[beg + it];
        unsigned c0 = p0 >> 17;
        const uint4* a0 = (j < 4) ? sT4 + (c0 >> 4) * 5 + js
                                  : cT4 + (c0 & 15) * 5 + jc;
        uint4 u = *a0;
        acc[0] += blo(u.x); acc[1] += bhi(u.x);
        acc[2] += blo(u.y); acc[3] += bhi(u.y);
        acc[4] += blo(u.z); acc[5] += bhi(u.z);
        acc[6] += blo(u.w); acc[7] += bhi(u.w);
    }
    float inv = 1.0f / fmaxf((float)deg, 1.0f);
    uint4 o;
    o.x = ((unsigned)f2b(acc[1] * inv) << 16) | f2b(acc[0] * inv);
    o.y = ((unsigned)f2b(acc[3] * inv) << 16) | f2b(acc[2] * inv);
    o.z = ((unsigned)f2b(acc[5] * inv) << 16) | f2b(acc[4] * inv);
    o.w = ((unsigned)f2b(acc[7] * inv) << 16) | f2b(acc[6] * inv);
    *reinterpret_cast<uint4*>(aggb + (size_t)node * 64 + j * 8) = o;
}

// Round 19: layer 1 GEMM with self term from LDS emb table (code[node]) --
// h is never materialized before this kernel. agg from bf16 aggb.
static __global__ __launch_bounds__(256) void layer1s_kernel(
        const float* __restrict__ semb, const float* __restrict__ cemb,
        const unsigned short* __restrict__ code,
        const unsigned short* __restrict__ aggb,
        const float* __restrict__ wl, const float* __restrict__ wr,
        const float* __restrict__ b,
        unsigned short* __restrict__ h, int n_nodes) {
    __shared__ __align__(16) unsigned sT[64 * 16];   // 4096B (stride 16: benign)
    __shared__ __align__(16) unsigned cT[16 * 16];   // 1024B
    __shared__ float inS[64][132];   // [node][k]: 0..63 agg, 64..127 self
    __shared__ float wS[128][64];    // rows 0..63 = wl, 64..127 = wr
    __shared__ unsigned short codeL[64];
    int t = threadIdx.x;
    int base = blockIdx.x * 64;

    for (int i = t; i < 64 * 16; i += 256) {
        int r = i >> 4, c = i & 15;
        float lo = semb[r * 32 + c * 2], hi = semb[r * 32 + c * 2 + 1];
        sT[r * 16 + c] = ((unsigned)f2b(hi) << 16) | f2b(lo);
    }
    for (int i = t; i < 16 * 16; i += 256) {
        int r = i >> 4, c = i & 15;
        float lo = cemb[r * 32 + c * 2], hi = cemb[r * 32 + c * 2 + 1];
        cT[r * 16 + c] = ((unsigned)f2b(hi) << 16) | f2b(lo);
    }
    const float4* wl4 = (const float4*)wl;
    const float4* wr4 = (const float4*)wr;
#pragma unroll
    for (int r = 0; r < 4; ++r) {
        int i = t + 256 * r;
        int k = i >> 4, c = (i & 15) * 4;
        *(float4*)&wS[k][c] = wl4[i];
        *(float4*)&wS[64 + k][c] = wr4[i];
    }
    if (t < 64) {
        int node = base + t;
        codeL[t] = (node < n_nodes) ? code[node] : 0;
    }
#pragma unroll
    for (int r = 0; r < 4; ++r) {
        int i = t + 256 * r;
        int n = i >> 4, c = (i & 15) * 4;
        int node = base + n;
        float4 va = make_float4(0.f, 0.f, 0.f, 0.f);
        if (node < n_nodes)
            va = b4_to_f4(*(const ushort4*)&aggb[(size_t)node * 64 + c]);
        *(float4*)&inS[n][c] = va;
    }
    __syncthreads();

    // self term from table row of code[n] (identical bf16 values to embed pass)
    for (int i = t; i < 64 * 16; i += 256) {
        int n = i >> 4, c4 = (i & 15) * 4;     // c4 in {0,4,...,60}
        unsigned cd = codeL[n];
        unsigned u0, u1;
        if (c4 < 32) {
            int idx = (cd >> 4) * 16 + (c4 >> 1);
            u0 = sT[idx]; u1 = sT[idx + 1];
        } else {
            int idx = (cd & 15) * 16 + ((c4 - 32) >> 1);
            u0 = cT[idx]; u1 = cT[idx + 1];
        }
        inS[n][64 + c4]     = blo(u0);
        inS[n][64 + c4 + 1] = bhi(u0);
        inS[n][64 + c4 + 2] = blo(u1);
        inS[n][64 + c4 + 3] = bhi(u1);
    }
    __syncthreads();

    int tx = t & 15, ty = t >> 4;
    int c0 = tx * 4, n0 = ty * 4;
    float4 bias = *(const float4*)&b[c0];
    float acc[4][4];
#pragma unroll
    for (int i = 0; i < 4; ++i) {
        acc[i][0] = bias.x; acc[i][1] = bias.y;
        acc[i][2] = bias.z; acc[i][3] = bias.w;
    }

#pragma unroll 4
    for (int k = 0; k < 128; k += 4) {
        float4 a0 = *(const float4*)&inS[n0 + 0][k];
        float4 a1 = *(const float4*)&inS[n0 + 1][k];
        float4 a2 = *(const float4*)&inS[n0 + 2][k];
        float4 a3 = *(const float4*)&inS[n0 + 3][k];
        float4 w0 = *(const float4*)&wS[k + 0][c0];
        float4 w1 = *(const float4*)&wS[k + 1][c0];
        float4 w2 = *(const float4*)&wS[k + 2][c0];
        float4 w3 = *(const float4*)&wS[k + 3][c0];
#define ROW(i, ai)                                                        \
        acc[i][0] = fmaf(ai.x, w0.x, fmaf(ai.y, w1.x, fmaf(ai.z, w2.x,    \
                    fmaf(ai.w, w3.x, acc[i][0]))));                       \
        acc[i][1] = fmaf(ai.x, w0.y, fmaf(ai.y, w1.y, fmaf(ai.z, w2.y,    \
                    fmaf(ai.w, w3.y, acc[i][1]))));                       \
        acc[i][2] = fmaf(ai.x, w0.z, fmaf(ai.y, w1.z, fmaf(ai.z, w2.z,    \
                    fmaf(ai.w, w3.z, acc[i][2]))));                       \
        acc[i][3] = fmaf(ai.x, w0.w, fmaf(ai.y, w1.w, fmaf(ai.z, w2.w,    \
                    fmaf(ai.w, w3.w, acc[i][3]))));
        ROW(0, a0) ROW(1, a1) ROW(2, a2) ROW(3, a3)
#undef ROW
    }

#pragma unroll
    for (int i = 0; i < 4; ++i) {
        int node = base + n0 + i;
        if (node < n_nodes) {
            ushort4 o;
            o.x = f2b(fmaxf(acc[i][0], 0.f));
            o.y = f2b(fmaxf(acc[i][1], 0.f));
            o.z = f2b(fmaxf(acc[i][2], 0.f));
            o.w = f2b(fmaxf(acc[i][3], 0.f));
            *(ushort4*)&h[(size_t)node * 64 + c0] = o;
        }
    }
}

// Layer-2 gather: group-per-node, 8 lanes/node, lane j cols [8j,8j+8).
static __global__ __launch_bounds__(256) void gather_kernel(
        const unsigned short* __restrict__ h, const int* __restrict__ startA,
        const int* __restrict__ cntA,
        const unsigned* __restrict__ csr_packed, unsigned short* __restrict__ aggb,
        int n_nodes) {
    int node = (blockIdx.x * 256 + threadIdx.x) >> 3;
    int j = threadIdx.x & 7;                 // cols [8j, 8j+8)
    if (node >= n_nodes) return;
    int beg = startA[node], deg = cntA[node];

    float acc[8];
#pragma unroll
    for (int k = 0; k < 8; ++k) acc[k] = 0.f;

    const unsigned short* hj = h + j * 8;
    int it = 0;
    for (; it + 1 < deg; it += 2) {
        int s0 = (int)(csr_packed[beg + it] & 0x1FFFFu);
        int s1 = (int)(csr_packed[beg + it + 1] & 0x1FFFFu);
        uint4 u0 = *reinterpret_cast<const uint4*>(hj + (size_t)s0 * 64);
        uint4 u1 = *reinterpret_cast<const uint4*>(hj + (size_t)s1 * 64);
        acc[0] += blo(u0.x) + blo(u1.x);
        acc[1] += bhi(u0.x) + bhi(u1.x);
        acc[2] += blo(u0.y) + blo(u1.y);
        acc[3] += bhi(u0.y) + bhi(u1.y);
        acc[4] += blo(u0.z) + blo(u1.z);
        acc[5] += bhi(u0.z) + bhi(u1.z);
        acc[6] += blo(u0.w) + blo(u1.w);
        acc[7] += bhi(u0.w) + bhi(u1.w);
    }
    if (it < deg) {
        int s = (int)(csr_packed[beg + it] & 0x1FFFFu);
        uint4 u = *reinterpret_cast<const uint4*>(hj + (size_t)s * 64);
        acc[0] += blo(u.x); acc[1] += bhi(u.x);
        acc[2] += blo(u.y); acc[3] += bhi(u.y);
        acc[4] += blo(u.z); acc[5] += bhi(u.z);
        acc[6] += blo(u.w); acc[7] += bhi(u.w);
    }
    float inv = 1.0f / fmaxf((float)deg, 1.0f);
    uint4 o;
    o.x = ((unsigned)f2b(acc[1] * inv) << 16) | f2b(acc[0] * inv);
    o.y = ((unsigned)f2b(acc[3] * inv) << 16) | f2b(acc[2] * inv);
    o.z = ((unsigned)f2b(acc[5] * inv) << 16) | f2b(acc[4] * inv);
    o.w = ((unsigned)f2b(acc[7] * inv) << 16) | f2b(acc[6] * inv);
    *reinterpret_cast<uint4*>(aggb + (size_t)node * 64 + j * 8) = o;
}

// h = relu([agg | h] @ [wl; wr] + b), in place (bf16 h + bf16 agg, fp32 math).
static __global__ __launch_bounds__(256) void layer_kernel(
        unsigned short* __restrict__ h, const unsigned short* __restrict__ aggb,
        const float* __restrict__ wl, const float* __restrict__ wr,
        const float* __restrict__ b, int n_nodes) {
    __shared__ float inS[64][132];   // [node][k], +4 pad
    __shared__ float wS[128][64];    // [k][col], rows 0..63 = wl, 64..127 = wr
    int t = threadIdx.x;
    int base = blockIdx.x * 64;

    const float4* wl4 = (const float4*)wl;
    const float4* wr4 = (const float4*)wr;
#pragma unroll
    for (int r = 0; r < 4; ++r) {
        int i = t + 256 * r;
        int k = i >> 4, c = (i & 15) * 4;
        *(float4*)&wS[k][c] = wl4[i];
        *(float4*)&wS[64 + k][c] = wr4[i];
    }
#pragma unroll
    for (int r = 0; r < 4; ++r) {
        int i = t + 256 * r;
        int n = i >> 4, c = (i & 15) * 4;
        int node = base + n;
        float4 va = make_float4(0.f, 0.f, 0.f, 0.f);
        float4 vh = make_float4(0.f, 0.f, 0.f, 0.f);
        if (node < n_nodes) {
            va = b4_to_f4(*(const ushort4*)&aggb[(size_t)node * 64 + c]);
            vh = b4_to_f4(*(const ushort4*)&h[(size_t)node * 64 + c]);
        }
        *(float4*)&inS[n][c] = va;
        *(float4*)&inS[n][64 + c] = vh;
    }
    __syncthreads();

    int tx = t & 15, ty = t >> 4;
    int c0 = tx * 4, n0 = ty * 4;
    float4 bias = *(const float4*)&b[c0];
    float acc[4][4];
#pragma unroll
    for (int i = 0; i < 4; ++i) {
        acc[i][0] = bias.x; acc[i][1] = bias.y;
        acc[i][2] = bias.z; acc[i][3] = bias.w;
    }

#pragma unroll 4
    for (int k = 0; k < 128; k += 4) {
        float4 a0 = *(const float4*)&inS[n0 + 0][k];
        float4 a1 = *(const float4*)&inS[n0 + 1][k];
        float4 a2 = *(const float4*)&inS[n0 + 2][k];
        float4 a3 = *(const float4*)&inS[n0 + 3][k];
        float4 w0 = *(const float4*)&wS[k + 0][c0];
        float4 w1 = *(const float4*)&wS[k + 1][c0];
        float4 w2 = *(const float4*)&wS[k + 2][c0];
        float4 w3 = *(const float4*)&wS[k + 3][c0];
#define ROW(i, ai)                                                        \
        acc[i][0] = fmaf(ai.x, w0.x, fmaf(ai.y, w1.x, fmaf(ai.z, w2.x,    \
                    fmaf(ai.w, w3.x, acc[i][0]))));                       \
        acc[i][1] = fmaf(ai.x, w0.y, fmaf(ai.y, w1.y, fmaf(ai.z, w2.y,    \
                    fmaf(ai.w, w3.y, acc[i][1]))));                       \
        acc[i][2] = fmaf(ai.x, w0.z, fmaf(ai.y, w1.z, fmaf(ai.z, w2.z,    \
                    fmaf(ai.w, w3.z, acc[i][2]))));                       \
        acc[i][3] = fmaf(ai.x, w0.w, fmaf(ai.y, w1.w, fmaf(ai.z, w2.w,    \
                    fmaf(ai.w, w3.w, acc[i][3]))));
        ROW(0, a0) ROW(1, a1) ROW(2, a2) ROW(3, a3)
#undef ROW
    }

#pragma unroll
    for (int i = 0; i < 4; ++i) {
        int node = base + n0 + i;
        if (node < n_nodes) {
            ushort4 o;
            o.x = f2b(fmaxf(acc[i][0], 0.f));
            o.y = f2b(fmaxf(acc[i][1], 0.f));
            o.z = f2b(fmaxf(acc[i][2], 0.f));
            o.w = f2b(fmaxf(acc[i][3], 0.f));
            *(ushort4*)&h[(size_t)node * 64 + c0] = o;
        }
    }
}

// batch is sorted: binary-search [start,end) per graph; mean-pool then classify.
static __global__ __launch_bounds__(256) void pool_classify_kernel(
        const unsigned short* __restrict__ h, const int* __restrict__ batch,
        const float* __restrict__ wc, const float* __restrict__ bc,
        void* __restrict__ out, const void* probe, int n_nodes) {
    int f32 = detect_f32(probe, 1024);
    int g = blockIdx.x;
    int t = threadIdx.x;
    int lo = 0, hi = n_nodes;
    while (lo < hi) { int mid = (lo + hi) >> 1; if (batch[mid] < g) lo = mid + 1; else hi = mid; }
    int start = lo;
    hi = n_nodes;
    while (lo < hi) { int mid = (lo + hi) >> 1; if (batch[mid] < g + 1) lo = mid + 1; else hi = mid; }
    int end = lo;

    int r = t >> 6, o = t & 63;
    float partial = 0.0f;
    for (int n = start + r; n < end; n += 4) partial += b2f(h[(size_t)n * 64 + o]);
    __shared__ float sred[4][64];
    __shared__ float pooled[64];
    sred[r][o] = partial;
    __syncthreads();
    if (r == 0) {
        float cntf = fmaxf((float)(end - start), 1.0f);
        pooled[o] = (sred[0][o] + sred[1][o] + sred[2][o] + sred[3][o]) / cntf;
    }
    __syncthreads();
    if (t < 10) {
        float acc = bc[t];
#pragma unroll
        for (int k = 0; k < 64; ++k)
            acc = fmaf(pooled[k], wc[k * 10 + t], acc);
        if (f32) ((float*)out)[g * 10 + t] = acc;
        else     ((__hip_bfloat16*)out)[g * 10 + t] = __float2bfloat16(acc);
    }
}

extern "C" void kernel_launch(void* const* d_in, const int* in_sizes, int n_in,
                              void* d_out, int out_size, void* d_ws, size_t ws_size,
                              hipStream_t stream) {
    const int* x          = (const int*)d_in[0];
    const int* edge_index = (const int*)d_in[1];
    const int* batch      = (const int*)d_in[2];

    const int N = in_sizes[2];        // N_NODES
    const int E = in_sizes[1] / 2;    // edge_index is (2, E)
    const int G = out_size / 10;      // num_graphs

    const int NBE = (E + 4095) / 4096;          // edge tiles
    const int Hsz = 512 * NBE;                  // histogram matrix size
    const int SB  = (Hsz + 511) / 512;          // scanA blocks (<=1024)
    const int CB  = (N + 255) / 256;            // code blocks

    // workspace layout
    unsigned short* h    = (unsigned short*)d_ws;           // N*64 bf16
    unsigned short* aggb = h + (size_t)N * 64;              // N*64 bf16
    unsigned* rec   = (unsigned*)(aggb + (size_t)N * 64);   // E packed
    int*   startA  = (int*)(rec + E);                       // N
    int*   cntA    = startA + N;                            // N
    int*   H       = cntA + N;                              // Hsz
    int*   B       = H + Hsz;                               // Hsz
    int*   tmpS    = B + Hsz;                               // Hsz
    int*   bsumS   = tmpS + Hsz;                            // SB (<=1024)
    unsigned* csr_packed = (unsigned*)(bsumS + 1024);       // E: (code<<17)|src
    unsigned short* code = (unsigned short*)(csr_packed + E); // N (padded to 4B)
    float* wbuf    = (float*)(code + (((size_t)N + 1) & ~(size_t)1));

    WParams wp;
    int off = 0;
    for (int i = 0; i < 10; ++i) {
        wp.p[i] = d_in[4 + i];
        wp.off[i] = off;
        off += in_sizes[4 + i];
    }
    wp.off[10] = off;
    const int wtotal = off;

    float* semb_f = wbuf + wp.off[0];
    float* cemb_f = wbuf + wp.off[1];
    float* w1l_f  = wbuf + wp.off[2];
    float* w1r_f  = wbuf + wp.off[3];
    float* b1_f   = wbuf + wp.off[4];
    float* w2l_f  = wbuf + wp.off[5];
    float* w2r_f  = wbuf + wp.off[6];
    float* b2_f   = wbuf + wp.off[7];
    float* wc_f   = wbuf + wp.off[8];
    float* bc_f   = wbuf + wp.off[9];

    const int* src = edge_index;
    const int* tgt = edge_index + E;

    convert_kernel<<<(wtotal + 255) / 256, 256, 0, stream>>>(wp, d_in[4], wbuf, wtotal);

    // CSR build by counting sort (no global returning atomics, no memset)
    hist1_code_kernel<<<NBE + CB, 256, 0, stream>>>(tgt, H, NBE, x, code, N, E);
    scanA_kernel<<<SB, 256, 0, stream>>>(H, tmpS, bsumS, Hsz);
    scanC_kernel<<<(Hsz + 255) / 256, 256, 0, stream>>>(tmpS, bsumS, H, B, Hsz);
    scatter1_kernel<<<NBE, 256, 0, stream>>>(src, tgt, B, rec, NBE, E);
    csr2_kernel<<<512, 256, 0, stream>>>(rec, B, NBE, code, csr_packed,
                                         startA, cntA, N, E);

    // layer 1 (high-occupancy gather + low-occupancy GEMM, separate kernels)
    gather1_kernel<<<(N * 8 + 255) / 256, 256, 0, stream>>>(semb_f, cemb_f,
                                                            startA, cntA,
                                                            csr_packed, aggb, N);
    layer1s_kernel<<<(N + 63) / 64, 256, 0, stream>>>(
        semb_f, cemb_f, code, aggb, w1l_f, w1r_f, b1_f, h, N);

    // layer 2
    gather_kernel<<<(N * 8 + 255) / 256, 256, 0, stream>>>(h, startA, cntA,
                                                           csr_packed, aggb, N);
    layer_kernel<<<(N + 63) / 64, 256, 0, stream>>>(h, aggb, w2l_f, w2r_f, b2_f, N);

    // pool + classify
    pool_classify_kernel<<<G, 256, 0, stream>>>(h, batch, wc_f, bc_f, d_out, d_in[4], N);
}

// Round 5
// 237.460 us; speedup vs baseline: 1.2676x; 1.1441x over previous
//
#include <hip/hip_runtime.h>
#include <hip/hip_bf16.h>

// SPRGraphNet: embed -> 2x SAGEConv(mean) -> mean-pool per graph -> linear(64->10)
// Inputs detected fp32 (round 2). bf16 h (round 8). Sort-based CSR (round 10).
// Round 16: group-per-node gather (8 lanes/node, no shfl reduce).
// Round 17: layer-1 gather via LDS embedding table (1024 distinct rows).
// Round 18: code-only pass, scan2 folded into scanC.
// Round 19: un-fused gather1 (gather needs occupancy; GEMM doesn't).
// Round 20: MFMA layer kernels. The fp32 LDS-tiled GEMM was LDS-throughput
// bound (~1MB LDS reads/block, 16x amplification -> ~30us/layer). Replaced
// with mfma_f32_16x16x32_bf16: A-frags straight from global bf16 rows
// (aggb | h or emb1024[code]), B-frags from wfrag (weights pre-swizzled into
// MFMA lane order by hist1_code's extra blocks; fp32 split hi+lo bf16 for
// ~2^-17 weight error). Zero LDS, no barriers, ~32 MFMA/wave.
// C/D layout (m89-verified): col=lane&15, row=(lane>>4)*4+reg.
// Harness poison fills (~84us/iter at 81% HBM peak) + per-iter restore
// dispatch overhead = floor.

typedef __attribute__((ext_vector_type(8))) short bf16x8;
typedef __attribute__((ext_vector_type(4))) float f32x4;

struct WParams {
    const void* p[10];
    int off[11];
};

__device__ __forceinline__ float b2f(unsigned short u) {
    return __uint_as_float(((unsigned)u) << 16);
}
__device__ __forceinline__ unsigned short f2b(float f) {
    unsigned x = __float_as_uint(f);
    return (unsigned short)((x + 0x7fff + ((x >> 16) & 1)) >> 16);   // RNE
}
__device__ __forceinline__ float blo(unsigned u) {   // low bf16 of a dword
    return __uint_as_float(u << 16);
}
__device__ __forceinline__ float bhi(unsigned u) {   // high bf16 of a dword
    return __uint_as_float(u & 0xffff0000u);
}

// Inline dtype detection: fp32 data read as bf16 shows |v|>100 / NaN.
__device__ __forceinline__ int detect_f32(const void* probe, int n_bf16) {
    __shared__ int bad;
    if (threadIdx.x == 0) bad = 0;
    __syncthreads();
    const __hip_bfloat16* p = (const __hip_bfloat16*)probe;
    int lbad = 0;
    for (int i = threadIdx.x; i < n_bf16; i += blockDim.x) {
        float v = __bfloat162float(p[i]);
        if (!(fabsf(v) <= 100.0f)) lbad = 1;
    }
    if (lbad) atomicOr(&bad, 1);
    __syncthreads();
    return bad;
}

__device__ __forceinline__ float loadf(const void* p, int i, int f32) {
    return f32 ? ((const float*)p)[i]
               : __bfloat162float(((const __hip_bfloat16*)p)[i]);
}

static __global__ void convert_kernel(WParams wp, const void* probe,
                                      float* __restrict__ dst, int total) {
    int f32 = detect_f32(probe, 1024);
    int gid = blockIdx.x * blockDim.x + threadIdx.x;
    if (gid >= total) return;
    int s = 0;
    while (gid >= wp.off[s + 1]) ++s;
    dst[gid] = loadf(wp.p[s], gid - wp.off[s], f32);
}

// Blocks [0,NBE): LDS histogram of tgt&511 over a 4096-edge tile -> H[bin][blk].
// Blocks [NBE,NBE+CB): code[node] = x0*16+x1.
// Blocks [NBE+CB, +16): emb1024 bf16 table ([semb[r>>4] | cemb[r&15]] rows).
// Blocks [NBE+CB+16, +8): wfrag: weights swizzled into MFMA B-frag lane order,
//   fp32 split into hi/lo bf16. Flat idx = ((((L*2+part)*4+ks)*4+nt)*64+lane)*8+j.
static __global__ __launch_bounds__(256) void hist1_code_kernel(
        const int* __restrict__ tgt, int* __restrict__ H, int NBE, int CB,
        const int* __restrict__ x, unsigned short* __restrict__ code,
        const float* __restrict__ semb, const float* __restrict__ cemb,
        const float* __restrict__ w1l, const float* __restrict__ w1r,
        const float* __restrict__ w2l, const float* __restrict__ w2r,
        unsigned short* __restrict__ emb1024, unsigned short* __restrict__ wfrag,
        int n_nodes, int n_edges) {
    int t = threadIdx.x;
    if (blockIdx.x < (unsigned)NBE) {
        __shared__ int lh[512];
        lh[t] = 0; lh[t + 256] = 0;
        __syncthreads();
        int base = blockIdx.x * 4096;              // multiple of 4
        const int4* tgt4 = (const int4*)tgt + (base >> 2);
#pragma unroll
        for (int r = 0; r < 4; ++r) {
            int i4 = t + 256 * r;
            int e = base + i4 * 4;
            if (e + 3 < n_edges) {
                int4 v = tgt4[i4];
                atomicAdd(&lh[v.x & 511], 1);
                atomicAdd(&lh[v.y & 511], 1);
                atomicAdd(&lh[v.z & 511], 1);
                atomicAdd(&lh[v.w & 511], 1);
            } else {
                for (int q = 0; q < 4; ++q) {
                    int ee = e + q;
                    if (ee < n_edges) atomicAdd(&lh[tgt[ee] & 511], 1);
                }
            }
        }
        __syncthreads();
        H[(size_t)t * NBE + blockIdx.x] = lh[t];
        H[(size_t)(t + 256) * NBE + blockIdx.x] = lh[t + 256];
    } else if (blockIdx.x < (unsigned)(NBE + CB)) {
        int node = (blockIdx.x - NBE) * 256 + t;
        if (node >= n_nodes) return;
        int2 xv = *(const int2*)&x[node * 2];
        code[node] = (unsigned short)(xv.x * 16 + xv.y);
    } else if (blockIdx.x < (unsigned)(NBE + CB + 16)) {
        int bl = blockIdx.x - NBE - CB;
        for (int i = bl * 256 + t; i < 1024 * 64; i += 16 * 256) {
            int r = i >> 6, c = i & 63;
            float v = (c < 32) ? semb[(r >> 4) * 32 + c]
                               : cemb[(r & 15) * 32 + (c - 32)];
            emb1024[i] = f2b(v);
        }
    } else {
        int bl = blockIdx.x - NBE - CB - 16;
        for (int i = bl * 256 + t; i < 32768; i += 8 * 256) {
            int j    = i & 7;
            int lane = (i >> 3) & 63;
            int nt   = (i >> 9) & 3;
            int ks   = (i >> 11) & 3;
            int part = (i >> 13) & 1;
            int L    = (i >> 14) & 1;
            int k = ks * 32 + (lane >> 4) * 8 + j;
            int c = nt * 16 + (lane & 15);
            const float* wl = L ? w2l : w1l;
            const float* wr = L ? w2r : w1r;
            float wv = (k < 64) ? wl[k * 64 + c] : wr[(k - 64) * 64 + c];
            unsigned short hi = f2b(wv);
            wfrag[i] = (part == 0) ? hi : f2b(wv - b2f(hi));
        }
    }
}

// scanA: 512 elements per block (2/thread), block-inclusive -> tmp, sums -> bsum.
static __global__ __launch_bounds__(256) void scanA_kernel(
        const int* __restrict__ in, int* __restrict__ tmp,
        int* __restrict__ bsum, int n) {
    __shared__ int s[256];
    int t = threadIdx.x;
    int i0 = blockIdx.x * 512 + 2 * t;
    int a0 = (i0 < n) ? in[i0] : 0;
    int a1 = (i0 + 1 < n) ? in[i0 + 1] : 0;
    s[t] = a0 + a1;
    __syncthreads();
#pragma unroll
    for (int d = 1; d < 256; d <<= 1) {
        int x = (t >= d) ? s[t - d] : 0;
        __syncthreads();
        s[t] += x;
        __syncthreads();
    }
    if (i0 < n) tmp[i0] = s[t] - a1;          // inclusive at i0
    if (i0 + 1 < n) tmp[i0 + 1] = s[t];       // inclusive at i0+1
    if (t == 255) bsum[blockIdx.x] = s[255];
}

// scanC: basep = sum of raw bsum[0..blk) per block; B[i] = tmp[i]+basep-H[i].
static __global__ __launch_bounds__(256) void scanC_kernel(
        const int* __restrict__ tmp, const int* __restrict__ bsum,
        const int* __restrict__ H, int* __restrict__ B, int n) {
    __shared__ int red[256];
    int t = threadIdx.x;
    int blk = blockIdx.x >> 1;        // 512-element scan block (constant/block)
    int partial = 0;
    for (int i = t; i < blk; i += 256) partial += bsum[i];
    red[t] = partial;
    __syncthreads();
#pragma unroll
    for (int d = 128; d > 0; d >>= 1) {
        if (t < d) red[t] += red[t + d];
        __syncthreads();
    }
    int basep = red[0];
    int i = blockIdx.x * 256 + t;
    if (i < n) B[i] = tmp[i] + basep - H[i];
}

// scatter1: re-read tile; LDS cursors seeded from B give global slots directly.
// Write packed 32-bit records ((tgt>>9)<<17 | src) grouped by bucket.
static __global__ __launch_bounds__(256) void scatter1_kernel(
        const int* __restrict__ src, const int* __restrict__ tgt,
        const int* __restrict__ B, unsigned* __restrict__ rec,
        int NBE, int n_edges) {
    __shared__ int cur[512];
    int t = threadIdx.x;
    cur[t]       = B[(size_t)t * NBE + blockIdx.x];
    cur[t + 256] = B[(size_t)(t + 256) * NBE + blockIdx.x];
    __syncthreads();
    int base = blockIdx.x * 4096;
    const int4* tgt4 = (const int4*)tgt + (base >> 2);
    const int4* src4 = (const int4*)src + (base >> 2);
#pragma unroll
    for (int r = 0; r < 4; ++r) {
        int i4 = t + 256 * r;
        int e = base + i4 * 4;
        if (e + 3 < n_edges) {
            int4 tv = tgt4[i4];
            int4 sv = src4[i4];
            int p0 = atomicAdd(&cur[tv.x & 511], 1);
            rec[p0] = ((unsigned)(tv.x >> 9) << 17) | (unsigned)sv.x;
            int p1 = atomicAdd(&cur[tv.y & 511], 1);
            rec[p1] = ((unsigned)(tv.y >> 9) << 17) | (unsigned)sv.y;
            int p2 = atomicAdd(&cur[tv.z & 511], 1);
            rec[p2] = ((unsigned)(tv.z >> 9) << 17) | (unsigned)sv.z;
            int p3 = atomicAdd(&cur[tv.w & 511], 1);
            rec[p3] = ((unsigned)(tv.w >> 9) << 17) | (unsigned)sv.w;
        } else {
            for (int q = 0; q < 4; ++q) {
                int ee = e + q;
                if (ee < n_edges) {
                    int tg = tgt[ee];
                    int pos = atomicAdd(&cur[tg & 511], 1);
                    rec[pos] = ((unsigned)(tg >> 9) << 17) | (unsigned)src[ee];
                }
            }
        }
    }
}

// csr2: one block per bucket b. Records [B[b*NBE], next) share tgt&511==b;
// q = rec>>17 (<196), node = b + (q<<9). LDS hist+scan -> start/cnt + scatter.
// Emits packed (code[src]<<17)|src so gathers need no node lookup.
static __global__ __launch_bounds__(256) void csr2_kernel(
        const unsigned* __restrict__ rec, const int* __restrict__ B,
        int NBE, const unsigned short* __restrict__ code,
        unsigned* __restrict__ csr_packed,
        int* __restrict__ startA, int* __restrict__ cntA,
        int n_nodes, int n_edges) {
    __shared__ int hist[256], scn[256], cursor[256];
    __shared__ int sbeg, send;
    int b = blockIdx.x;
    int t = threadIdx.x;
    hist[t] = 0;
    if (t == 0) {
        sbeg = B[(size_t)b * NBE];
        send = (b == 511) ? n_edges : B[(size_t)(b + 1) * NBE];
    }
    __syncthreads();
    int beg = sbeg, end = send;
    for (int i = beg + t; i < end; i += 256) {
        atomicAdd(&hist[rec[i] >> 17], 1);
    }
    __syncthreads();
    scn[t] = hist[t];
    __syncthreads();
#pragma unroll
    for (int d = 1; d < 256; d <<= 1) {
        int x = (t >= d) ? scn[t - d] : 0;
        __syncthreads();
        scn[t] += x;
        __syncthreads();
    }
    int excl = scn[t] - hist[t];
    cursor[t] = beg + excl;
    int n = b + (t << 9);
    if (n < n_nodes) { startA[n] = beg + excl; cntA[n] = hist[t]; }
    __syncthreads();
    for (int i = beg + t; i < end; i += 256) {
        unsigned r = rec[i];
        unsigned s = r & 0x1FFFFu;
        unsigned cd = code[s];                 // 200KB table, L2-resident
        int p = atomicAdd(&cursor[r >> 17], 1);
        csr_packed[p] = (cd << 17) | s;
    }
}

// Layer-1 gather from LDS embedding table. 8 lanes per node; lane j owns cols
// [8j,8j+8). Row for code c is [semb[c>>4] | cemb[c&15]]. Writes bf16 aggb.
static __global__ __launch_bounds__(256) void gather1_kernel(
        const float* __restrict__ semb, const float* __restrict__ cemb,
        const int* __restrict__ startA, const int* __restrict__ cntA,
        const unsigned* __restrict__ csr_packed, unsigned short* __restrict__ aggb,
        int n_nodes) {
    __shared__ __align__(16) unsigned sT[64 * 20];   // 5120B
    __shared__ __align__(16) unsigned cT[16 * 20];   // 1280B
    int t = threadIdx.x;
    for (int i = t; i < 64 * 16; i += 256) {
        int r = i >> 4, c = i & 15;
        float lo = semb[r * 32 + c * 2], hi = semb[r * 32 + c * 2 + 1];
        sT[r * 20 + c] = ((unsigned)f2b(hi) << 16) | f2b(lo);
    }
    for (int i = t; i < 16 * 16; i += 256) {
        int r = i >> 4, c = i & 15;
        float lo = cemb[r * 32 + c * 2], hi = cemb[r * 32 + c * 2 + 1];
        cT[r * 20 + c] = ((unsigned)f2b(hi) << 16) | f2b(lo);
    }
    __syncthreads();

    int node = (blockIdx.x * 256 + t) >> 3;
    int j = t & 7;                           // cols [8j, 8j+8)
    if (node >= n_nodes) return;
    int beg = startA[node], deg = cntA[node];

    const uint4* sT4 = (const uint4*)sT;     // row = 5 uint4
    const uint4* cT4 = (const uint4*)cT;
    int js = j, jc = j - 4;                  // lane's block within sub-table

    float acc[8];
#pragma unroll
    for (int k = 0; k < 8; ++k) acc[k] = 0.f;

    int it = 0;
    for (; it + 1 < deg; it += 2) {
        unsigned p0 = csr_packed[beg + it];
        unsigned p1 = csr_packed[beg + it + 1];
        unsigned c0 = p0 >> 17, c1 = p1 >> 17;
        const uint4* a0 = (j < 4) ? sT4 + (c0 >> 4) * 5 + js
                                  : cT4 + (c0 & 15) * 5 + jc;
        const uint4* a1 = (j < 4) ? sT4 + (c1 >> 4) * 5 + js
                                  : cT4 + (c1 & 15) * 5 + jc;
        uint4 u0 = *a0;
        uint4 u1 = *a1;
        acc[0] += blo(u0.x) + blo(u1.x);
        acc[1] += bhi(u0.x) + bhi(u1.x);
        acc[2] += blo(u0.y) + blo(u1.y);
        acc[3] += bhi(u0.y) + bhi(u1.y);
        acc[4] += blo(u0.z) + blo(u1.z);
        acc[5] += bhi(u0.z) + bhi(u1.z);
        acc[6] += blo(u0.w) + blo(u1.w);
        acc[7] += bhi(u0.w) + bhi(u1.w);
    }
    if (it < deg) {
        unsigned p0 = csr_packed[beg + it];
        unsigned c0 = p0 >> 17;
        const uint4* a0 = (j < 4) ? sT4 + (c0 >> 4) * 5 + js
                                  : cT4 + (c0 & 15) * 5 + jc;
        uint4 u = *a0;
        acc[0] += blo(u.x); acc[1] += bhi(u.x);
        acc[2] += blo(u.y); acc[3] += bhi(u.y);
        acc[4] += blo(u.z); acc[5] += bhi(u.z);
        acc[6] += blo(u.w); acc[7] += bhi(u.w);
    }
    float inv = 1.0f / fmaxf((float)deg, 1.0f);
    uint4 o;
    o.x = ((unsigned)f2b(acc[1] * inv) << 16) | f2b(acc[0] * inv);
    o.y = ((unsigned)f2b(acc[3] * inv) << 16) | f2b(acc[2] * inv);
    o.z = ((unsigned)f2b(acc[5] * inv) << 16) | f2b(acc[4] * inv);
    o.w = ((unsigned)f2b(acc[7] * inv) << 16) | f2b(acc[6] * inv);
    *reinterpret_cast<uint4*>(aggb + (size_t)node * 64 + j * 8) = o;
}

// Layer-2 gather: group-per-node, 8 lanes/node, lane j cols [8j,8j+8).
static __global__ __launch_bounds__(256) void gather_kernel(
        const unsigned short* __restrict__ h, const int* __restrict__ startA,
        const int* __restrict__ cntA,
        const unsigned* __restrict__ csr_packed, unsigned short* __restrict__ aggb,
        int n_nodes) {
    int node = (blockIdx.x * 256 + threadIdx.x) >> 3;
    int j = threadIdx.x & 7;                 // cols [8j, 8j+8)
    if (node >= n_nodes) return;
    int beg = startA[node], deg = cntA[node];

    float acc[8];
#pragma unroll
    for (int k = 0; k < 8; ++k) acc[k] = 0.f;

    const unsigned short* hj = h + j * 8;
    int it = 0;
    for (; it + 1 < deg; it += 2) {
        int s0 = (int)(csr_packed[beg + it] & 0x1FFFFu);
        int s1 = (int)(csr_packed[beg + it + 1] & 0x1FFFFu);
        uint4 u0 = *reinterpret_cast<const uint4*>(hj + (size_t)s0 * 64);
        uint4 u1 = *reinterpret_cast<const uint4*>(hj + (size_t)s1 * 64);
        acc[0] += blo(u0.x) + blo(u1.x);
        acc[1] += bhi(u0.x) + bhi(u1.x);
        acc[2] += blo(u0.y) + blo(u1.y);
        acc[3] += bhi(u0.y) + bhi(u1.y);
        acc[4] += blo(u0.z) + blo(u1.z);
        acc[5] += bhi(u0.z) + bhi(u1.z);
        acc[6] += blo(u0.w) + blo(u1.w);
        acc[7] += bhi(u0.w) + bhi(u1.w);
    }
    if (it < deg) {
        int s = (int)(csr_packed[beg + it] & 0x1FFFFu);
        uint4 u = *reinterpret_cast<const uint4*>(hj + (size_t)s * 64);
        acc[0] += blo(u.x); acc[1] += bhi(u.x);
        acc[2] += blo(u.y); acc[3] += bhi(u.y);
        acc[4] += blo(u.z); acc[5] += bhi(u.z);
        acc[6] += blo(u.w); acc[7] += bhi(u.w);
    }
    float inv = 1.0f / fmaxf((float)deg, 1.0f);
    uint4 o;
    o.x = ((unsigned)f2b(acc[1] * inv) << 16) | f2b(acc[0] * inv);
    o.y = ((unsigned)f2b(acc[3] * inv) << 16) | f2b(acc[2] * inv);
    o.z = ((unsigned)f2b(acc[5] * inv) << 16) | f2b(acc[4] * inv);
    o.w = ((unsigned)f2b(acc[7] * inv) << 16) | f2b(acc[6] * inv);
    *reinterpret_cast<uint4*>(aggb + (size_t)node * 64 + j * 8) = o;
}

// Round 20: MFMA layer. Block = 256 threads = 4 waves; wave w owns 16 nodes
// [base+16w, base+16w+16). M=16,N=64,K=128 per wave via 4 k-steps x 4 n-tiles
// x {hi,lo} mfma_f32_16x16x32_bf16. A-frag: lane l = row (l&15) of
// [aggb row | self row], k = ks*32+(l>>4)*8.. (ks 0-1: aggb, ks 2-3: self).
// self = h row (layer2) or emb1024[code[node]&1023] (layer1, use_code).
// B-frag: wfrag pre-swizzled, offset ((((part)*4+ks)*4+nt)*64+l)*8.
// Epilogue: D col=l&15 (+nt*16), row=(l>>4)*4+reg; bias+relu+f2b -> hout.
static __global__ __launch_bounds__(256) void layer_mfma_kernel(
        const unsigned short* __restrict__ aggb,
        const unsigned short* __restrict__ selfsrc,
        const unsigned short* __restrict__ code,
        const unsigned short* __restrict__ wfrag,
        const float* __restrict__ bias,
        unsigned short* __restrict__ hout, int n_nodes, int use_code) {
    int t = threadIdx.x;
    int w = t >> 6, l = t & 63;
    int row16 = l & 15, kb = l >> 4;          // kb in 0..3
    int base = blockIdx.x * 64 + w * 16;
    int node = base + row16;                  // A-row node (may be OOB; reads safe)

    const unsigned short* selfrow;
    if (use_code) {
        unsigned cd = (unsigned)code[node] & 1023u;
        selfrow = selfsrc + (size_t)cd * 64;
    } else {
        selfrow = selfsrc + (size_t)node * 64;
    }
    const unsigned short* aggrow = aggb + (size_t)node * 64;

    f32x4 acc0 = {0.f, 0.f, 0.f, 0.f};
    f32x4 acc1 = {0.f, 0.f, 0.f, 0.f};
    f32x4 acc2 = {0.f, 0.f, 0.f, 0.f};
    f32x4 acc3 = {0.f, 0.f, 0.f, 0.f};

#pragma unroll
    for (int ks = 0; ks < 4; ++ks) {
        int koff = ks * 32 + kb * 8;
        const unsigned short* ap = (ks < 2) ? (aggrow + koff)
                                            : (selfrow + (koff - 64));
        bf16x8 a = *(const bf16x8*)ap;
        const unsigned short* wfh = wfrag + ((size_t)(0 * 4 + ks) * 4 * 64 + l) * 8;
        const unsigned short* wfl = wfrag + ((size_t)(1 * 4 + ks) * 4 * 64 + l) * 8;
#define NTILE(nt, accv)                                                          \
        {                                                                        \
            bf16x8 bh = *(const bf16x8*)(wfh + (size_t)nt * 64 * 8);             \
            bf16x8 bl = *(const bf16x8*)(wfl + (size_t)nt * 64 * 8);             \
            accv = __builtin_amdgcn_mfma_f32_16x16x32_bf16(a, bh, accv, 0, 0, 0);\
            accv = __builtin_amdgcn_mfma_f32_16x16x32_bf16(a, bl, accv, 0, 0, 0);\
        }
        NTILE(0, acc0) NTILE(1, acc1) NTILE(2, acc2) NTILE(3, acc3)
#undef NTILE
    }

#pragma unroll
    for (int nt = 0; nt < 4; ++nt) {
        f32x4 av = (nt == 0) ? acc0 : (nt == 1) ? acc1 : (nt == 2) ? acc2 : acc3;
        int col = nt * 16 + row16;
        float bv = bias[col];
#pragma unroll
        for (int r = 0; r < 4; ++r) {
            int orow = kb * 4 + r;
            int onode = blockIdx.x * 64 + w * 16 + orow;
            if (onode < n_nodes) {
                float v = fmaxf(av[r] + bv, 0.f);
                hout[(size_t)onode * 64 + col] = f2b(v);
            }
        }
    }
}

// batch is sorted: binary-search [start,end) per graph; mean-pool then classify.
static __global__ __launch_bounds__(256) void pool_classify_kernel(
        const unsigned short* __restrict__ h, const int* __restrict__ batch,
        const float* __restrict__ wc, const float* __restrict__ bc,
        void* __restrict__ out, const void* probe, int n_nodes) {
    int f32 = detect_f32(probe, 1024);
    int g = blockIdx.x;
    int t = threadIdx.x;
    int lo = 0, hi = n_nodes;
    while (lo < hi) { int mid = (lo + hi) >> 1; if (batch[mid] < g) lo = mid + 1; else hi = mid; }
    int start = lo;
    hi = n_nodes;
    while (lo < hi) { int mid = (lo + hi) >> 1; if (batch[mid] < g + 1) lo = mid + 1; else hi = mid; }
    int end = lo;

    int r = t >> 6, o = t & 63;
    float partial = 0.0f;
    for (int n = start + r; n < end; n += 4) partial += b2f(h[(size_t)n * 64 + o]);
    __shared__ float sred[4][64];
    __shared__ float pooled[64];
    sred[r][o] = partial;
    __syncthreads();
    if (r == 0) {
        float cntf = fmaxf((float)(end - start), 1.0f);
        pooled[o] = (sred[0][o] + sred[1][o] + sred[2][o] + sred[3][o]) / cntf;
    }
    __syncthreads();
    if (t < 10) {
        float acc = bc[t];
#pragma unroll
        for (int k = 0; k < 64; ++k)
            acc = fmaf(pooled[k], wc[k * 10 + t], acc);
        if (f32) ((float*)out)[g * 10 + t] = acc;
        else     ((__hip_bfloat16*)out)[g * 10 + t] = __float2bfloat16(acc);
    }
}

extern "C" void kernel_launch(void* const* d_in, const int* in_sizes, int n_in,
                              void* d_out, int out_size, void* d_ws, size_t ws_size,
                              hipStream_t stream) {
    const int* x          = (const int*)d_in[0];
    const int* edge_index = (const int*)d_in[1];
    const int* batch      = (const int*)d_in[2];

    const int N = in_sizes[2];        // N_NODES
    const int E = in_sizes[1] / 2;    // edge_index is (2, E)
    const int G = out_size / 10;      // num_graphs

    const int NBE = (E + 4095) / 4096;          // edge tiles
    const int Hsz = 512 * NBE;                  // histogram matrix size
    const int SB  = (Hsz + 511) / 512;          // scanA blocks (<=1024)
    const int CB  = (N + 255) / 256;            // code blocks

    // workspace layout
    unsigned short* h    = (unsigned short*)d_ws;           // N*64 bf16
    unsigned short* aggb = h + (size_t)N * 64;              // N*64 bf16
    unsigned* rec   = (unsigned*)(aggb + (size_t)N * 64);   // E packed
    int*   startA  = (int*)(rec + E);                       // N
    int*   cntA    = startA + N;                            // N
    int*   H       = cntA + N;                              // Hsz
    int*   B       = H + Hsz;                               // Hsz
    int*   tmpS    = B + Hsz;                               // Hsz
    int*   bsumS   = tmpS + Hsz;                            // SB (<=1024)
    unsigned* csr_packed = (unsigned*)(bsumS + 1024);       // E: (code<<17)|src
    unsigned short* code = (unsigned short*)(csr_packed + E); // N ushorts
    size_t NP = ((size_t)N + 7) & ~(size_t)7;               // 16B-align next
    unsigned short* emb1024 = code + NP;                    // 1024*64 bf16
    unsigned short* wfrag   = emb1024 + 1024 * 64;          // 2*2*4*4*64*8 bf16
    float* wbuf    = (float*)(wfrag + 32768);

    WParams wp;
    int off = 0;
    for (int i = 0; i < 10; ++i) {
        wp.p[i] = d_in[4 + i];
        wp.off[i] = off;
        off += in_sizes[4 + i];
    }
    wp.off[10] = off;
    const int wtotal = off;

    float* semb_f = wbuf + wp.off[0];
    float* cemb_f = wbuf + wp.off[1];
    float* w1l_f  = wbuf + wp.off[2];
    float* w1r_f  = wbuf + wp.off[3];
    float* b1_f   = wbuf + wp.off[4];
    float* w2l_f  = wbuf + wp.off[5];
    float* w2r_f  = wbuf + wp.off[6];
    float* b2_f   = wbuf + wp.off[7];
    float* wc_f   = wbuf + wp.off[8];
    float* bc_f   = wbuf + wp.off[9];

    const int* src = edge_index;
    const int* tgt = edge_index + E;

    convert_kernel<<<(wtotal + 255) / 256, 256, 0, stream>>>(wp, d_in[4], wbuf, wtotal);

    // CSR build + code + emb1024 + wfrag (single multi-role launch)
    hist1_code_kernel<<<NBE + CB + 24, 256, 0, stream>>>(
        tgt, H, NBE, CB, x, code, semb_f, cemb_f, w1l_f, w1r_f, w2l_f, w2r_f,
        emb1024, wfrag, N, E);
    scanA_kernel<<<SB, 256, 0, stream>>>(H, tmpS, bsumS, Hsz);
    scanC_kernel<<<(Hsz + 255) / 256, 256, 0, stream>>>(tmpS, bsumS, H, B, Hsz);
    scatter1_kernel<<<NBE, 256, 0, stream>>>(src, tgt, B, rec, NBE, E);
    csr2_kernel<<<512, 256, 0, stream>>>(rec, B, NBE, code, csr_packed,
                                         startA, cntA, N, E);

    // layer 1: gather (high occupancy) + MFMA GEMM (emb1024 self via code)
    gather1_kernel<<<(N * 8 + 255) / 256, 256, 0, stream>>>(semb_f, cemb_f,
                                                            startA, cntA,
                                                            csr_packed, aggb, N);
    layer_mfma_kernel<<<(N + 63) / 64, 256, 0, stream>>>(
        aggb, emb1024, code, wfrag, b1_f, h, N, 1);

    // layer 2: gather from h + MFMA GEMM (self = h rows)
    gather_kernel<<<(N * 8 + 255) / 256, 256, 0, stream>>>(h, startA, cntA,
                                                           csr_packed, aggb, N);
    layer_mfma_kernel<<<(N + 63) / 64, 256, 0, stream>>>(
        aggb, h, code, wfrag + 16384, b2_f, h, N, 0);

    // pool + classify
    pool_classify_kernel<<<G, 256, 0, stream>>>(h, batch, wc_f, bc_f, d_out, d_in[4], N);
}

// Round 6
// 237.442 us; speedup vs baseline: 1.2677x; 1.0001x over previous
//
#include <hip/hip_runtime.h>
#include <hip/hip_bf16.h>

// SPRGraphNet: embed -> 2x SAGEConv(mean) -> mean-pool per graph -> linear(64->10)
// Round 16: group-per-node gather. Round 17: LDS emb table for gather1.
// Round 18: code-only pass, folded scan. Round 19: un-fused gather1.
// Round 20: MFMA layer kernels (wfrag pre-swizzled hi/lo bf16 weights).
// Round 21: (a) gather kernels 4-deep MLP (2-deep left BW at ~3.2 TB/s eff;
// Little's law says ~2x outstanding loads needed); (b) convert_kernel launch
// removed -- emb1024/wfrag/params roles in hist1_code read RAW inputs with
// inline detect_f32; gather1 stages its LDS table from emb1024 directly.
// 10 launches. Harness poison fills (~85us/iter at 80% HBM peak) = floor.

typedef __attribute__((ext_vector_type(8))) short bf16x8;
typedef __attribute__((ext_vector_type(4))) float f32x4;

struct WParams {
    const void* p[10];
    int off[11];
};

__device__ __forceinline__ float b2f(unsigned short u) {
    return __uint_as_float(((unsigned)u) << 16);
}
__device__ __forceinline__ unsigned short f2b(float f) {
    unsigned x = __float_as_uint(f);
    return (unsigned short)((x + 0x7fff + ((x >> 16) & 1)) >> 16);   // RNE
}
__device__ __forceinline__ float blo(unsigned u) {   // low bf16 of a dword
    return __uint_as_float(u << 16);
}
__device__ __forceinline__ float bhi(unsigned u) {   // high bf16 of a dword
    return __uint_as_float(u & 0xffff0000u);
}

// Inline dtype detection: fp32 data read as bf16 shows |v|>100 / NaN.
__device__ __forceinline__ int detect_f32(const void* probe, int n_bf16) {
    __shared__ int bad;
    if (threadIdx.x == 0) bad = 0;
    __syncthreads();
    const __hip_bfloat16* p = (const __hip_bfloat16*)probe;
    int lbad = 0;
    for (int i = threadIdx.x; i < n_bf16; i += blockDim.x) {
        float v = __bfloat162float(p[i]);
        if (!(fabsf(v) <= 100.0f)) lbad = 1;
    }
    if (lbad) atomicOr(&bad, 1);
    __syncthreads();
    return bad;
}

__device__ __forceinline__ float loadf(const void* p, int i, int f32) {
    return f32 ? ((const float*)p)[i]
               : __bfloat162float(((const __hip_bfloat16*)p)[i]);
}

// Blocks [0,NBE): LDS histogram of tgt&511 over a 4096-edge tile -> H[bin][blk].
// Blocks [NBE,NBE+CB): code[node] = x0*16+x1.
// Blocks [NBE+CB, +16): emb1024 bf16 table from RAW semb/cemb (detect inline).
// Blocks [NBE+CB+16, +8): wfrag (MFMA B-frag swizzled, hi/lo bf16) from RAW.
// Block  [NBE+CB+24]: pbuf fp32 params: b1[0,64) b2[64,128) wc[128,768) bc[768,778).
static __global__ __launch_bounds__(256) void hist1_code_kernel(
        const int* __restrict__ tgt, int* __restrict__ H, int NBE, int CB,
        const int* __restrict__ x, unsigned short* __restrict__ code,
        WParams wp,
        unsigned short* __restrict__ emb1024, unsigned short* __restrict__ wfrag,
        float* __restrict__ pbuf, int n_nodes, int n_edges) {
    int t = threadIdx.x;
    if (blockIdx.x < (unsigned)NBE) {
        __shared__ int lh[512];
        lh[t] = 0; lh[t + 256] = 0;
        __syncthreads();
        int base = blockIdx.x * 4096;              // multiple of 4
        const int4* tgt4 = (const int4*)tgt + (base >> 2);
#pragma unroll
        for (int r = 0; r < 4; ++r) {
            int i4 = t + 256 * r;
            int e = base + i4 * 4;
            if (e + 3 < n_edges) {
                int4 v = tgt4[i4];
                atomicAdd(&lh[v.x & 511], 1);
                atomicAdd(&lh[v.y & 511], 1);
                atomicAdd(&lh[v.z & 511], 1);
                atomicAdd(&lh[v.w & 511], 1);
            } else {
                for (int q = 0; q < 4; ++q) {
                    int ee = e + q;
                    if (ee < n_edges) atomicAdd(&lh[tgt[ee] & 511], 1);
                }
            }
        }
        __syncthreads();
        H[(size_t)t * NBE + blockIdx.x] = lh[t];
        H[(size_t)(t + 256) * NBE + blockIdx.x] = lh[t + 256];
    } else if (blockIdx.x < (unsigned)(NBE + CB)) {
        int node = (blockIdx.x - NBE) * 256 + t;
        if (node >= n_nodes) return;
        int2 xv = *(const int2*)&x[node * 2];
        code[node] = (unsigned short)(xv.x * 16 + xv.y);
    } else if (blockIdx.x < (unsigned)(NBE + CB + 16)) {
        int f32 = detect_f32(wp.p[0], 1024);
        int bl = blockIdx.x - NBE - CB;
        for (int i = bl * 256 + t; i < 1024 * 64; i += 16 * 256) {
            int r = i >> 6, c = i & 63;
            float v = (c < 32) ? loadf(wp.p[0], (r >> 4) * 32 + c, f32)
                               : loadf(wp.p[1], (r & 15) * 32 + (c - 32), f32);
            emb1024[i] = f2b(v);
        }
    } else if (blockIdx.x < (unsigned)(NBE + CB + 24)) {
        int f32 = detect_f32(wp.p[0], 1024);
        int bl = blockIdx.x - NBE - CB - 16;
        for (int i = bl * 256 + t; i < 32768; i += 8 * 256) {
            int j    = i & 7;
            int lane = (i >> 3) & 63;
            int nt   = (i >> 9) & 3;
            int ks   = (i >> 11) & 3;
            int part = (i >> 13) & 1;
            int L    = (i >> 14) & 1;
            int k = ks * 32 + (lane >> 4) * 8 + j;
            int c = nt * 16 + (lane & 15);
            const void* wl = L ? wp.p[5] : wp.p[2];
            const void* wr = L ? wp.p[6] : wp.p[3];
            float wv = (k < 64) ? loadf(wl, k * 64 + c, f32)
                                : loadf(wr, (k - 64) * 64 + c, f32);
            unsigned short hi = f2b(wv);
            wfrag[i] = (part == 0) ? hi : f2b(wv - b2f(hi));
        }
    } else {
        int f32 = detect_f32(wp.p[0], 1024);
        for (int i = t; i < 778; i += 256) {
            float v;
            if (i < 64)       v = loadf(wp.p[4], i, f32);         // b1
            else if (i < 128) v = loadf(wp.p[7], i - 64, f32);    // b2
            else if (i < 768) v = loadf(wp.p[8], i - 128, f32);   // wc
            else              v = loadf(wp.p[9], i - 768, f32);   // bc
            pbuf[i] = v;
        }
    }
}

// scanA: 512 elements per block (2/thread), block-inclusive -> tmp, sums -> bsum.
static __global__ __launch_bounds__(256) void scanA_kernel(
        const int* __restrict__ in, int* __restrict__ tmp,
        int* __restrict__ bsum, int n) {
    __shared__ int s[256];
    int t = threadIdx.x;
    int i0 = blockIdx.x * 512 + 2 * t;
    int a0 = (i0 < n) ? in[i0] : 0;
    int a1 = (i0 + 1 < n) ? in[i0 + 1] : 0;
    s[t] = a0 + a1;
    __syncthreads();
#pragma unroll
    for (int d = 1; d < 256; d <<= 1) {
        int x = (t >= d) ? s[t - d] : 0;
        __syncthreads();
        s[t] += x;
        __syncthreads();
    }
    if (i0 < n) tmp[i0] = s[t] - a1;          // inclusive at i0
    if (i0 + 1 < n) tmp[i0 + 1] = s[t];       // inclusive at i0+1
    if (t == 255) bsum[blockIdx.x] = s[255];
}

// scanC: basep = sum of raw bsum[0..blk) per block; B[i] = tmp[i]+basep-H[i].
static __global__ __launch_bounds__(256) void scanC_kernel(
        const int* __restrict__ tmp, const int* __restrict__ bsum,
        const int* __restrict__ H, int* __restrict__ B, int n) {
    __shared__ int red[256];
    int t = threadIdx.x;
    int blk = blockIdx.x >> 1;        // 512-element scan block (constant/block)
    int partial = 0;
    for (int i = t; i < blk; i += 256) partial += bsum[i];
    red[t] = partial;
    __syncthreads();
#pragma unroll
    for (int d = 128; d > 0; d >>= 1) {
        if (t < d) red[t] += red[t + d];
        __syncthreads();
    }
    int basep = red[0];
    int i = blockIdx.x * 256 + t;
    if (i < n) B[i] = tmp[i] + basep - H[i];
}

// scatter1: re-read tile; LDS cursors seeded from B give global slots directly.
// Write packed 32-bit records ((tgt>>9)<<17 | src) grouped by bucket.
static __global__ __launch_bounds__(256) void scatter1_kernel(
        const int* __restrict__ src, const int* __restrict__ tgt,
        const int* __restrict__ B, unsigned* __restrict__ rec,
        int NBE, int n_edges) {
    __shared__ int cur[512];
    int t = threadIdx.x;
    cur[t]       = B[(size_t)t * NBE + blockIdx.x];
    cur[t + 256] = B[(size_t)(t + 256) * NBE + blockIdx.x];
    __syncthreads();
    int base = blockIdx.x * 4096;
    const int4* tgt4 = (const int4*)tgt + (base >> 2);
    const int4* src4 = (const int4*)src + (base >> 2);
#pragma unroll
    for (int r = 0; r < 4; ++r) {
        int i4 = t + 256 * r;
        int e = base + i4 * 4;
        if (e + 3 < n_edges) {
            int4 tv = tgt4[i4];
            int4 sv = src4[i4];
            int p0 = atomicAdd(&cur[tv.x & 511], 1);
            rec[p0] = ((unsigned)(tv.x >> 9) << 17) | (unsigned)sv.x;
            int p1 = atomicAdd(&cur[tv.y & 511], 1);
            rec[p1] = ((unsigned)(tv.y >> 9) << 17) | (unsigned)sv.y;
            int p2 = atomicAdd(&cur[tv.z & 511], 1);
            rec[p2] = ((unsigned)(tv.z >> 9) << 17) | (unsigned)sv.z;
            int p3 = atomicAdd(&cur[tv.w & 511], 1);
            rec[p3] = ((unsigned)(tv.w >> 9) << 17) | (unsigned)sv.w;
        } else {
            for (int q = 0; q < 4; ++q) {
                int ee = e + q;
                if (ee < n_edges) {
                    int tg = tgt[ee];
                    int pos = atomicAdd(&cur[tg & 511], 1);
                    rec[pos] = ((unsigned)(tg >> 9) << 17) | (unsigned)src[ee];
                }
            }
        }
    }
}

// csr2: one block per bucket b. Records [B[b*NBE], next) share tgt&511==b;
// q = rec>>17 (<196), node = b + (q<<9). LDS hist+scan -> start/cnt + scatter.
// Emits packed (code[src]<<17)|src so gathers need no node lookup.
static __global__ __launch_bounds__(256) void csr2_kernel(
        const unsigned* __restrict__ rec, const int* __restrict__ B,
        int NBE, const unsigned short* __restrict__ code,
        unsigned* __restrict__ csr_packed,
        int* __restrict__ startA, int* __restrict__ cntA,
        int n_nodes, int n_edges) {
    __shared__ int hist[256], scn[256], cursor[256];
    __shared__ int sbeg, send;
    int b = blockIdx.x;
    int t = threadIdx.x;
    hist[t] = 0;
    if (t == 0) {
        sbeg = B[(size_t)b * NBE];
        send = (b == 511) ? n_edges : B[(size_t)(b + 1) * NBE];
    }
    __syncthreads();
    int beg = sbeg, end = send;
    for (int i = beg + t; i < end; i += 256) {
        atomicAdd(&hist[rec[i] >> 17], 1);
    }
    __syncthreads();
    scn[t] = hist[t];
    __syncthreads();
#pragma unroll
    for (int d = 1; d < 256; d <<= 1) {
        int x = (t >= d) ? scn[t - d] : 0;
        __syncthreads();
        scn[t] += x;
        __syncthreads();
    }
    int excl = scn[t] - hist[t];
    cursor[t] = beg + excl;
    int n = b + (t << 9);
    if (n < n_nodes) { startA[n] = beg + excl; cntA[n] = hist[t]; }
    __syncthreads();
    for (int i = beg + t; i < end; i += 256) {
        unsigned r = rec[i];
        unsigned s = r & 0x1FFFFu;
        unsigned cd = code[s];                 // 200KB table, L2-resident
        int p = atomicAdd(&cursor[r >> 17], 1);
        csr_packed[p] = (cd << 17) | s;
    }
}

// Layer-1 gather from LDS embedding table (staged from emb1024). 8 lanes per
// node; lane j owns cols [8j,8j+8). Row stride 20 uints for bank spread.
// 4-deep MLP pipeline. Writes bf16 aggb.
static __global__ __launch_bounds__(256) void gather1_kernel(
        const unsigned short* __restrict__ emb1024,
        const int* __restrict__ startA, const int* __restrict__ cntA,
        const unsigned* __restrict__ csr_packed, unsigned short* __restrict__ aggb,
        int n_nodes) {
    __shared__ __align__(16) unsigned sT[64 * 20];   // 5120B
    __shared__ __align__(16) unsigned cT[16 * 20];   // 1280B
    int t = threadIdx.x;
    const unsigned* e32 = (const unsigned*)emb1024;  // row = 32 uints
    for (int i = t; i < 64 * 16; i += 256) {
        int r = i >> 4, c = i & 15;
        sT[r * 20 + c] = e32[(size_t)(r * 16) * 32 + c];
    }
    for (int i = t; i < 16 * 16; i += 256) {
        int r = i >> 4, c = i & 15;
        cT[r * 20 + c] = e32[(size_t)r * 32 + 16 + c];
    }
    __syncthreads();

    int node = (blockIdx.x * 256 + t) >> 3;
    int j = t & 7;                           // cols [8j, 8j+8)
    if (node >= n_nodes) return;
    int beg = startA[node], deg = cntA[node];

    const uint4* sT4 = (const uint4*)sT;     // row = 5 uint4
    const uint4* cT4 = (const uint4*)cT;
    int js = j, jc = j - 4;                  // lane's block within sub-table

    float acc[8];
#pragma unroll
    for (int k = 0; k < 8; ++k) acc[k] = 0.f;

    int it = 0;
    for (; it + 3 < deg; it += 4) {
        unsigned p0 = csr_packed[beg + it];
        unsigned p1 = csr_packed[beg + it + 1];
        unsigned p2 = csr_packed[beg + it + 2];
        unsigned p3 = csr_packed[beg + it + 3];
        unsigned c0 = p0 >> 17, c1 = p1 >> 17, c2 = p2 >> 17, c3 = p3 >> 17;
        uint4 u0 = (j < 4) ? sT4[(c0 >> 4) * 5 + js] : cT4[(c0 & 15) * 5 + jc];
        uint4 u1 = (j < 4) ? sT4[(c1 >> 4) * 5 + js] : cT4[(c1 & 15) * 5 + jc];
        uint4 u2 = (j < 4) ? sT4[(c2 >> 4) * 5 + js] : cT4[(c2 & 15) * 5 + jc];
        uint4 u3 = (j < 4) ? sT4[(c3 >> 4) * 5 + js] : cT4[(c3 & 15) * 5 + jc];
        acc[0] += (blo(u0.x) + blo(u1.x)) + (blo(u2.x) + blo(u3.x));
        acc[1] += (bhi(u0.x) + bhi(u1.x)) + (bhi(u2.x) + bhi(u3.x));
        acc[2] += (blo(u0.y) + blo(u1.y)) + (blo(u2.y) + blo(u3.y));
        acc[3] += (bhi(u0.y) + bhi(u1.y)) + (bhi(u2.y) + bhi(u3.y));
        acc[4] += (blo(u0.z) + blo(u1.z)) + (blo(u2.z) + blo(u3.z));
        acc[5] += (bhi(u0.z) + bhi(u1.z)) + (bhi(u2.z) + bhi(u3.z));
        acc[6] += (blo(u0.w) + blo(u1.w)) + (blo(u2.w) + blo(u3.w));
        acc[7] += (bhi(u0.w) + bhi(u1.w)) + (bhi(u2.w) + bhi(u3.w));
    }
    for (; it < deg; ++it) {
        unsigned p0 = csr_packed[beg + it];
        unsigned c0 = p0 >> 17;
        uint4 u = (j < 4) ? sT4[(c0 >> 4) * 5 + js] : cT4[(c0 & 15) * 5 + jc];
        acc[0] += blo(u.x); acc[1] += bhi(u.x);
        acc[2] += blo(u.y); acc[3] += bhi(u.y);
        acc[4] += blo(u.z); acc[5] += bhi(u.z);
        acc[6] += blo(u.w); acc[7] += bhi(u.w);
    }
    float inv = 1.0f / fmaxf((float)deg, 1.0f);
    uint4 o;
    o.x = ((unsigned)f2b(acc[1] * inv) << 16) | f2b(acc[0] * inv);
    o.y = ((unsigned)f2b(acc[3] * inv) << 16) | f2b(acc[2] * inv);
    o.z = ((unsigned)f2b(acc[5] * inv) << 16) | f2b(acc[4] * inv);
    o.w = ((unsigned)f2b(acc[7] * inv) << 16) | f2b(acc[6] * inv);
    *reinterpret_cast<uint4*>(aggb + (size_t)node * 64 + j * 8) = o;
}

// Layer-2 gather: group-per-node, 8 lanes/node, lane j cols [8j,8j+8).
// 4-deep MLP pipeline (2-deep left effective BW at ~3.2 TB/s).
static __global__ __launch_bounds__(256) void gather_kernel(
        const unsigned short* __restrict__ h, const int* __restrict__ startA,
        const int* __restrict__ cntA,
        const unsigned* __restrict__ csr_packed, unsigned short* __restrict__ aggb,
        int n_nodes) {
    int node = (blockIdx.x * 256 + threadIdx.x) >> 3;
    int j = threadIdx.x & 7;                 // cols [8j, 8j+8)
    if (node >= n_nodes) return;
    int beg = startA[node], deg = cntA[node];

    float acc[8];
#pragma unroll
    for (int k = 0; k < 8; ++k) acc[k] = 0.f;

    const unsigned short* hj = h + j * 8;
    int it = 0;
    for (; it + 3 < deg; it += 4) {
        int s0 = (int)(csr_packed[beg + it] & 0x1FFFFu);
        int s1 = (int)(csr_packed[beg + it + 1] & 0x1FFFFu);
        int s2 = (int)(csr_packed[beg + it + 2] & 0x1FFFFu);
        int s3 = (int)(csr_packed[beg + it + 3] & 0x1FFFFu);
        uint4 u0 = *reinterpret_cast<const uint4*>(hj + (size_t)s0 * 64);
        uint4 u1 = *reinterpret_cast<const uint4*>(hj + (size_t)s1 * 64);
        uint4 u2 = *reinterpret_cast<const uint4*>(hj + (size_t)s2 * 64);
        uint4 u3 = *reinterpret_cast<const uint4*>(hj + (size_t)s3 * 64);
        acc[0] += (blo(u0.x) + blo(u1.x)) + (blo(u2.x) + blo(u3.x));
        acc[1] += (bhi(u0.x) + bhi(u1.x)) + (bhi(u2.x) + bhi(u3.x));
        acc[2] += (blo(u0.y) + blo(u1.y)) + (blo(u2.y) + blo(u3.y));
        acc[3] += (bhi(u0.y) + bhi(u1.y)) + (bhi(u2.y) + bhi(u3.y));
        acc[4] += (blo(u0.z) + blo(u1.z)) + (blo(u2.z) + blo(u3.z));
        acc[5] += (bhi(u0.z) + bhi(u1.z)) + (bhi(u2.z) + bhi(u3.z));
        acc[6] += (blo(u0.w) + blo(u1.w)) + (blo(u2.w) + blo(u3.w));
        acc[7] += (bhi(u0.w) + bhi(u1.w)) + (bhi(u2.w) + bhi(u3.w));
    }
    for (; it < deg; ++it) {
        int s = (int)(csr_packed[beg + it] & 0x1FFFFu);
        uint4 u = *reinterpret_cast<const uint4*>(hj + (size_t)s * 64);
        acc[0] += blo(u.x); acc[1] += bhi(u.x);
        acc[2] += blo(u.y); acc[3] += bhi(u.y);
        acc[4] += blo(u.z); acc[5] += bhi(u.z);
        acc[6] += blo(u.w); acc[7] += bhi(u.w);
    }
    float inv = 1.0f / fmaxf((float)deg, 1.0f);
    uint4 o;
    o.x = ((unsigned)f2b(acc[1] * inv) << 16) | f2b(acc[0] * inv);
    o.y = ((unsigned)f2b(acc[3] * inv) << 16) | f2b(acc[2] * inv);
    o.z = ((unsigned)f2b(acc[5] * inv) << 16) | f2b(acc[4] * inv);
    o.w = ((unsigned)f2b(acc[7] * inv) << 16) | f2b(acc[6] * inv);
    *reinterpret_cast<uint4*>(aggb + (size_t)node * 64 + j * 8) = o;
}

// MFMA layer. Block = 4 waves; wave w owns 16 nodes. M=16,N=64,K=128 via
// 4 k-steps x 4 n-tiles x {hi,lo} mfma_f32_16x16x32_bf16. A-frag from global
// bf16 rows (aggb | self); B-frag from wfrag. self = h row (layer2) or
// emb1024[code[node]] (layer1). D: col=lane&15 (+nt*16), row=(lane>>4)*4+reg.
static __global__ __launch_bounds__(256) void layer_mfma_kernel(
        const unsigned short* __restrict__ aggb,
        const unsigned short* __restrict__ selfsrc,
        const unsigned short* __restrict__ code,
        const unsigned short* __restrict__ wfrag,
        const float* __restrict__ bias,
        unsigned short* __restrict__ hout, int n_nodes, int use_code) {
    int t = threadIdx.x;
    int w = t >> 6, l = t & 63;
    int row16 = l & 15, kb = l >> 4;          // kb in 0..3
    int base = blockIdx.x * 64 + w * 16;
    int node = base + row16;                  // A-row node (may be OOB; reads safe)

    const unsigned short* selfrow;
    if (use_code) {
        unsigned cd = (unsigned)code[node] & 1023u;
        selfrow = selfsrc + (size_t)cd * 64;
    } else {
        selfrow = selfsrc + (size_t)node * 64;
    }
    const unsigned short* aggrow = aggb + (size_t)node * 64;

    f32x4 acc0 = {0.f, 0.f, 0.f, 0.f};
    f32x4 acc1 = {0.f, 0.f, 0.f, 0.f};
    f32x4 acc2 = {0.f, 0.f, 0.f, 0.f};
    f32x4 acc3 = {0.f, 0.f, 0.f, 0.f};

#pragma unroll
    for (int ks = 0; ks < 4; ++ks) {
        int koff = ks * 32 + kb * 8;
        const unsigned short* ap = (ks < 2) ? (aggrow + koff)
                                            : (selfrow + (koff - 64));
        bf16x8 a = *(const bf16x8*)ap;
        const unsigned short* wfh = wfrag + ((size_t)(0 * 4 + ks) * 4 * 64 + l) * 8;
        const unsigned short* wfl = wfrag + ((size_t)(1 * 4 + ks) * 4 * 64 + l) * 8;
#define NTILE(nt, accv)                                                          \
        {                                                                        \
            bf16x8 bh = *(const bf16x8*)(wfh + (size_t)nt * 64 * 8);             \
            bf16x8 bl = *(const bf16x8*)(wfl + (size_t)nt * 64 * 8);             \
            accv = __builtin_amdgcn_mfma_f32_16x16x32_bf16(a, bh, accv, 0, 0, 0);\
            accv = __builtin_amdgcn_mfma_f32_16x16x32_bf16(a, bl, accv, 0, 0, 0);\
        }
        NTILE(0, acc0) NTILE(1, acc1) NTILE(2, acc2) NTILE(3, acc3)
#undef NTILE
    }

#pragma unroll
    for (int nt = 0; nt < 4; ++nt) {
        f32x4 av = (nt == 0) ? acc0 : (nt == 1) ? acc1 : (nt == 2) ? acc2 : acc3;
        int col = nt * 16 + row16;
        float bv = bias[col];
#pragma unroll
        for (int r = 0; r < 4; ++r) {
            int orow = kb * 4 + r;
            int onode = blockIdx.x * 64 + w * 16 + orow;
            if (onode < n_nodes) {
                float v = fmaxf(av[r] + bv, 0.f);
                hout[(size_t)onode * 64 + col] = f2b(v);
            }
        }
    }
}

// batch is sorted: binary-search [start,end) per graph; mean-pool then classify.
static __global__ __launch_bounds__(256) void pool_classify_kernel(
        const unsigned short* __restrict__ h, const int* __restrict__ batch,
        const float* __restrict__ wc, const float* __restrict__ bc,
        void* __restrict__ out, const void* probe, int n_nodes) {
    int f32 = detect_f32(probe, 1024);
    int g = blockIdx.x;
    int t = threadIdx.x;
    int lo = 0, hi = n_nodes;
    while (lo < hi) { int mid = (lo + hi) >> 1; if (batch[mid] < g) lo = mid + 1; else hi = mid; }
    int start = lo;
    hi = n_nodes;
    while (lo < hi) { int mid = (lo + hi) >> 1; if (batch[mid] < g + 1) lo = mid + 1; else hi = mid; }
    int end = lo;

    int r = t >> 6, o = t & 63;
    float partial = 0.0f;
    for (int n = start + r; n < end; n += 4) partial += b2f(h[(size_t)n * 64 + o]);
    __shared__ float sred[4][64];
    __shared__ float pooled[64];
    sred[r][o] = partial;
    __syncthreads();
    if (r == 0) {
        float cntf = fmaxf((float)(end - start), 1.0f);
        pooled[o] = (sred[0][o] + sred[1][o] + sred[2][o] + sred[3][o]) / cntf;
    }
    __syncthreads();
    if (t < 10) {
        float acc = bc[t];
#pragma unroll
        for (int k = 0; k < 64; ++k)
            acc = fmaf(pooled[k], wc[k * 10 + t], acc);
        if (f32) ((float*)out)[g * 10 + t] = acc;
        else     ((__hip_bfloat16*)out)[g * 10 + t] = __float2bfloat16(acc);
    }
}

extern "C" void kernel_launch(void* const* d_in, const int* in_sizes, int n_in,
                              void* d_out, int out_size, void* d_ws, size_t ws_size,
                              hipStream_t stream) {
    const int* x          = (const int*)d_in[0];
    const int* edge_index = (const int*)d_in[1];
    const int* batch      = (const int*)d_in[2];

    const int N = in_sizes[2];        // N_NODES
    const int E = in_sizes[1] / 2;    // edge_index is (2, E)
    const int G = out_size / 10;      // num_graphs

    const int NBE = (E + 4095) / 4096;          // edge tiles
    const int Hsz = 512 * NBE;                  // histogram matrix size
    const int SB  = (Hsz + 511) / 512;          // scanA blocks (<=1024)
    const int CB  = (N + 255) / 256;            // code blocks

    // workspace layout
    unsigned short* h    = (unsigned short*)d_ws;           // N*64 bf16
    unsigned short* aggb = h + (size_t)N * 64;              // N*64 bf16
    unsigned* rec   = (unsigned*)(aggb + (size_t)N * 64);   // E packed
    int*   startA  = (int*)(rec + E);                       // N
    int*   cntA    = startA + N;                            // N
    int*   H       = cntA + N;                              // Hsz
    int*   B       = H + Hsz;                               // Hsz
    int*   tmpS    = B + Hsz;                               // Hsz
    int*   bsumS   = tmpS + Hsz;                            // SB (<=1024)
    unsigned* csr_packed = (unsigned*)(bsumS + 1024);       // E: (code<<17)|src
    unsigned short* code = (unsigned short*)(csr_packed + E); // N ushorts
    size_t NP = ((size_t)N + 7) & ~(size_t)7;               // 16B-align next
    unsigned short* emb1024 = code + NP;                    // 1024*64 bf16
    unsigned short* wfrag   = emb1024 + 1024 * 64;          // 2*2*4*4*64*8 bf16
    float* pbuf    = (float*)(wfrag + 32768);               // 778 fp32 params

    WParams wp;
    int off = 0;
    for (int i = 0; i < 10; ++i) {
        wp.p[i] = d_in[4 + i];
        wp.off[i] = off;
        off += in_sizes[4 + i];
    }
    wp.off[10] = off;

    const int* src = edge_index;
    const int* tgt = edge_index + E;

    // CSR hist + code + emb1024 + wfrag + params (single multi-role launch)
    hist1_code_kernel<<<NBE + CB + 25, 256, 0, stream>>>(
        tgt, H, NBE, CB, x, code, wp, emb1024, wfrag, pbuf, N, E);
    scanA_kernel<<<SB, 256, 0, stream>>>(H, tmpS, bsumS, Hsz);
    scanC_kernel<<<(Hsz + 255) / 256, 256, 0, stream>>>(tmpS, bsumS, H, B, Hsz);
    scatter1_kernel<<<NBE, 256, 0, stream>>>(src, tgt, B, rec, NBE, E);
    csr2_kernel<<<512, 256, 0, stream>>>(rec, B, NBE, code, csr_packed,
                                         startA, cntA, N, E);

    // layer 1: gather (high occupancy, LDS table from emb1024) + MFMA GEMM
    gather1_kernel<<<(N * 8 + 255) / 256, 256, 0, stream>>>(emb1024,
                                                            startA, cntA,
                                                            csr_packed, aggb, N);
    layer_mfma_kernel<<<(N + 63) / 64, 256, 0, stream>>>(
        aggb, emb1024, code, wfrag, pbuf, h, N, 1);

    // layer 2: gather from h + MFMA GEMM (self = h rows)
    gather_kernel<<<(N * 8 + 255) / 256, 256, 0, stream>>>(h, startA, cntA,
                                                           csr_packed, aggb, N);
    layer_mfma_kernel<<<(N + 63) / 64, 256, 0, stream>>>(
        aggb, h, code, wfrag + 16384, pbuf + 64, h, N, 0);

    // pool + classify
    pool_classify_kernel<<<G, 256, 0, stream>>>(h, batch, pbuf + 128, pbuf + 768,
                                                d_out, d_in[4], N);
}